// Round 12
// baseline (535.373 us; speedup 1.0000x reference)
//
#include <hip/hip_runtime.h>
#include <hip/hip_bf16.h>
#include <math.h>

#define N_NODES 50000
#define N_EDGES 400000
#define E_TOT   (N_EDGES + N_NODES)   // self loops appended
#define HEADS   8
#define HID     64
#define HC      (HEADS * HID)         // 512
#define NBLK    ((N_NODES + 255) / 256)  // 196 scan blocks

typedef __attribute__((ext_vector_type(8))) short bf16x8;  // 8 bf16 (4 VGPRs)
typedef __attribute__((ext_vector_type(4))) float f32x4;

__device__ __forceinline__ float elu1(float x) { return x > 0.f ? x : __expf(x) - 1.f; }

// round-to-nearest-even fp32 -> bf16 (raw ushort)
__device__ __forceinline__ unsigned short f2bf(float x) {
    unsigned u = __float_as_uint(x);
    unsigned r = (u + 0x7FFFu + ((u >> 16) & 1u)) >> 16;
    return (unsigned short)r;
}
__device__ __forceinline__ float bf2f(unsigned short h) {
    return __uint_as_float(((unsigned)h) << 16);
}

// ---------------- CSR build (by dst) ----------------
__global__ void hist_kernel(const int* __restrict__ dst, int* __restrict__ deg) {
    int e = blockIdx.x * blockDim.x + threadIdx.x;
    if (e >= E_TOT) return;
    int d = (e < N_EDGES) ? dst[e] : (e - N_EDGES);
    atomicAdd(&deg[d], 1);
}

__global__ __launch_bounds__(256) void deg_partial_kernel(const int* __restrict__ deg,
                                                          int* __restrict__ psum) {
    __shared__ int sm[256];
    int t = threadIdx.x;
    int idx = blockIdx.x * 256 + t;
    int v = (idx < N_NODES) ? deg[idx] : 0;
    sm[t] = v;
    __syncthreads();
    for (int off = 128; off >= 1; off >>= 1) {
        if (t < off) sm[t] += sm[t + off];
        __syncthreads();
    }
    if (t == 0) psum[blockIdx.x] = sm[0];
}

__global__ __launch_bounds__(256) void scan_partial_kernel(int* __restrict__ psum) {
    __shared__ int sm[256];
    int t = threadIdx.x;
    int v = (t < NBLK) ? psum[t] : 0;
    sm[t] = v;
    __syncthreads();
    for (int off = 1; off < 256; off <<= 1) {
        int add = (t >= off) ? sm[t - off] : 0;
        __syncthreads();
        sm[t] += add;
        __syncthreads();
    }
    if (t < NBLK) psum[t] = sm[t] - v;  // exclusive
}

__global__ __launch_bounds__(256) void rowptr_kernel(const int* __restrict__ deg,
                                                     const int* __restrict__ psum,
                                                     int* __restrict__ rowptr,
                                                     int* __restrict__ cursor) {
    __shared__ int sm[256];
    int t = threadIdx.x;
    int idx = blockIdx.x * 256 + t;
    int v = (idx < N_NODES) ? deg[idx] : 0;
    sm[t] = v;
    __syncthreads();
    for (int off = 1; off < 256; off <<= 1) {
        int add = (t >= off) ? sm[t - off] : 0;
        __syncthreads();
        sm[t] += add;
        __syncthreads();
    }
    if (idx < N_NODES) {
        int r = psum[blockIdx.x] + sm[t] - v;  // exclusive
        rowptr[idx] = r;
        cursor[idx] = r;
    }
    if (idx == 0) rowptr[N_NODES] = E_TOT;
}

__global__ void scatter_kernel(const int* __restrict__ srcrow, const int* __restrict__ dstrow,
                               int* __restrict__ cursor, int* __restrict__ src_sorted) {
    int e = blockIdx.x * blockDim.x + threadIdx.x;
    if (e >= E_TOT) return;
    int s, d;
    if (e < N_EDGES) { s = srcrow[e]; d = dstrow[e]; }
    else             { s = d = e - N_EDGES; }
    int pos = atomicAdd(&cursor[d], 1);
    src_sorted[pos] = s;
}

// ---------------- Layer 1 GEMM: [N,5] @ [5,512] -> bf16 h ----------------
__global__ void gemm5_kernel(const float* __restrict__ x, const float* __restrict__ W,
                             unsigned short* __restrict__ h) {
    int gid = blockIdx.x * blockDim.x + threadIdx.x;
    if (gid >= N_NODES * HC) return;
    int n = gid >> 9, c = gid & 511;
    const float* xr = x + n * 5;
    float acc = xr[0] * W[c] + xr[1] * W[512 + c] + xr[2] * W[1024 + c] +
                xr[3] * W[1536 + c] + xr[4] * W[2048 + c];
    h[gid] = f2bf(acc);
}

// ---------------- W -> W^T bf16: W[512][NCOL] -> Wt[NCOL][512] ----------------
template <int NCOL>
__global__ void wtrans_kernel(const float* __restrict__ W, unsigned short* __restrict__ hi) {
    int idx = blockIdx.x * 256 + threadIdx.x;
    if (idx >= 512 * NCOL) return;
    int k = idx / NCOL, n = idx % NCOL;
    hi[(size_t)n * 512 + k] = f2bf(W[idx]);
}

// ---------------- bf16 MFMA GEMM: bf16 A x bf16 W^T, BK=64 full-line staging ----------------
// LDS rows of 64B; 16B-slot p holds k-chunk g = p ^ ((row>>1)&3) (zero-conflict, R5-measured).
// Full 128B-line staging per row via back-to-back half-chunks (R6).
template <int ROWS, int NW>
__device__ __forceinline__ void stage_pair(const unsigned short* __restrict__ src, int row0,
                                           int maxRow, int k0, char* lds0, char* lds1,
                                           int wave, int lane) {
    constexpr int CHUNKS = ROWS / 16;  // 1KB chunks (16 rows x 64B) per half
    for (int c = wave; c < CHUNKS; c += NW) {
        int r = c * 16 + (lane >> 2);
        int p = lane & 3;
        int g = p ^ ((r >> 1) & 3);
        int gr = row0 + r;
        if (gr > maxRow) gr = maxRow;  // tail clamp; result write-guarded
        const unsigned short* gp = src + (size_t)gr * 512 + k0 + g * 8;
        __builtin_amdgcn_global_load_lds((const __attribute__((address_space(1))) void*)gp,
                                         (__attribute__((address_space(3))) void*)(lds0 + c * 1024),
                                         16, 0, 0);
        __builtin_amdgcn_global_load_lds((const __attribute__((address_space(1))) void*)(gp + 32),
                                         (__attribute__((address_space(3))) void*)(lds1 + c * 1024),
                                         16, 0, 0);
    }
}

// 1D grid, y-grouped XCD swizzle (T1): blocks sharing an A panel (same by, bx=0..GX-1)
// get wg % 8 == by % 8 -> same XCD -> A-panel L2 reuse instead of GX-way HBM re-fetch.
template <int BM, int BN, int WM, int WN, int GX>
__global__ __launch_bounds__(WM * WN * 64) void gemm_mfma(
    const unsigned short* __restrict__ A, const unsigned short* __restrict__ B,
    unsigned short* __restrict__ C, int M, int Nout, int maxRowB) {
    constexpr int NW = WM * WN;
    constexpr int MI = BM / (16 * WM);
    constexpr int NI = BN / (16 * WN);
    constexpr int ABYTES = BM * 64;
    constexpr int BBYTES = BN * 64;
    constexpr int GRPS = GX * 8;
    __shared__ __attribute__((aligned(16))) char lds[(ABYTES + BBYTES) * 2];
    char* const pA0 = lds;
    char* const pA1 = pA0 + ABYTES;
    char* const pB0 = pA1 + ABYTES;
    char* const pB1 = pB0 + BBYTES;

    const int wg = blockIdx.x;
    const int bx = (wg % GRPS) >> 3;
    const int by = (wg / GRPS) * 8 + (wg & 7);
    if (by * BM >= M) return;  // whole block exits before any barrier
    const int m0 = by * BM, n0 = bx * BN;

    const int t = threadIdx.x, lane = t & 63, wave = t >> 6;
    const int wr = wave / WN, wc = wave % WN;

    int offA[MI], offB[NI];
#pragma unroll
    for (int s = 0; s < MI; ++s) {
        int rA = (wr * MI + s) * 16 + (lane & 15);
        offA[s] = rA * 64 + ((((lane >> 4) ^ ((rA >> 1) & 3))) << 4);
    }
#pragma unroll
    for (int s = 0; s < NI; ++s) {
        int rB = (wc * NI + s) * 16 + (lane & 15);
        offB[s] = rB * 64 + ((((lane >> 4) ^ ((rB >> 1) & 3))) << 4);
    }

    f32x4 acc[MI][NI] = {};

    for (int k0 = 0; k0 < 512; k0 += 64) {
        stage_pair<BM, NW>(A, m0, M - 1,   k0, pA0, pA1, wave, lane);
        stage_pair<BN, NW>(B, n0, maxRowB, k0, pB0, pB1, wave, lane);
        __syncthreads();  // compiler drains vmcnt before barrier -> LDS valid

#pragma unroll
        for (int half = 0; half < 2; ++half) {
            const char* cA = half ? pA1 : pA0;
            const char* cB = half ? pB1 : pB0;
            bf16x8 av[MI], bv[NI];
#pragma unroll
            for (int s = 0; s < MI; ++s) av[s] = *(const bf16x8*)(cA + offA[s]);
#pragma unroll
            for (int s = 0; s < NI; ++s) bv[s] = *(const bf16x8*)(cB + offB[s]);
#pragma unroll
            for (int i = 0; i < MI; ++i)
#pragma unroll
                for (int j = 0; j < NI; ++j)
                    acc[i][j] = __builtin_amdgcn_mfma_f32_16x16x32_bf16(av[i], bv[j], acc[i][j], 0, 0, 0);
        }
        __syncthreads();
    }

    // C/D layout (m89-verified): col = lane&15, row = (lane>>4)*4 + reg
#pragma unroll
    for (int i = 0; i < MI; ++i) {
        int row = m0 + (wr * MI + i) * 16 + ((lane >> 4) << 2);
#pragma unroll
        for (int j = 0; j < NI; ++j) {
            int col = n0 + (wc * NI + j) * 16 + (lane & 15);
            f32x4 v = acc[i][j];
#pragma unroll
            for (int r = 0; r < 4; ++r) {
                if (row + r < M) C[(size_t)(row + r) * Nout + col] = f2bf(v[r]);
            }
        }
    }
}

// ---------------- attention scores from bf16 h: s_src/s_dst [N,H] ----------------
template <int H>
__global__ void score_kernel(const unsigned short* __restrict__ h,
                             const float* __restrict__ a_src, const float* __restrict__ a_dst,
                             float* __restrict__ ssrc, float* __restrict__ sdst) {
    int gid = blockIdx.x * blockDim.x + threadIdx.x;
    if (gid >= N_NODES * H) return;
    int n = gid / H, hh = gid % H;
    const unsigned short* hp = h + (size_t)n * (H * 64) + hh * 64;
    const float* asp = a_src + hh * 64;
    const float* adp = a_dst + hh * 64;
    float s1 = 0.f, s2 = 0.f;
#pragma unroll
    for (int k = 0; k < 64; k += 8) {
        uint4 hv = *(const uint4*)(hp + k);
        const unsigned u[4] = {hv.x, hv.y, hv.z, hv.w};
#pragma unroll
        for (int q = 0; q < 4; ++q) {
            float f0 = bf2f((unsigned short)(u[q] & 0xffff));
            float f1 = bf2f((unsigned short)(u[q] >> 16));
            s1 = fmaf(f0, asp[k + 2 * q], fmaf(f1, asp[k + 2 * q + 1], s1));
            s2 = fmaf(f0, adp[k + 2 * q], fmaf(f1, adp[k + 2 * q + 1], s2));
        }
    }
    ssrc[gid] = s1;
    sdst[gid] = s2;
}

// ---------------- per-(dst,head) softmax (4-wide gather pipeline, R7-proven) ----------------
template <int H>
__global__ void softmax_kernel(const int* __restrict__ rowptr, const int* __restrict__ srcs,
                               const float* __restrict__ ssrc, const float* __restrict__ sdst,
                               float* __restrict__ p, float* __restrict__ rden) {
    int gid = blockIdx.x * blockDim.x + threadIdx.x;
    if (gid >= N_NODES * H) return;
    int n = gid / H, hh = gid % H;
    int lo = rowptr[n], hi = rowptr[n + 1];
    float sd = sdst[gid];
    float m0 = -3.4e38f, m1 = -3.4e38f, m2 = -3.4e38f, m3 = -3.4e38f;
    int j = lo;
    for (; j + 4 <= hi; j += 4) {
        int s0 = srcs[j], s1 = srcs[j + 1], s2 = srcs[j + 2], s3 = srcs[j + 3];
        float v0 = ssrc[s0 * H + hh] + sd;
        float v1 = ssrc[s1 * H + hh] + sd;
        float v2 = ssrc[s2 * H + hh] + sd;
        float v3 = ssrc[s3 * H + hh] + sd;
        v0 = v0 > 0.f ? v0 : 0.2f * v0;
        v1 = v1 > 0.f ? v1 : 0.2f * v1;
        v2 = v2 > 0.f ? v2 : 0.2f * v2;
        v3 = v3 > 0.f ? v3 : 0.2f * v3;
        p[(size_t)j * H + hh] = v0;
        p[(size_t)(j + 1) * H + hh] = v1;
        p[(size_t)(j + 2) * H + hh] = v2;
        p[(size_t)(j + 3) * H + hh] = v3;
        m0 = fmaxf(m0, v0); m1 = fmaxf(m1, v1);
        m2 = fmaxf(m2, v2); m3 = fmaxf(m3, v3);
    }
    for (; j < hi; ++j) {
        float v = ssrc[srcs[j] * H + hh] + sd;
        v = v > 0.f ? v : 0.2f * v;
        p[(size_t)j * H + hh] = v;
        m0 = fmaxf(m0, v);
    }
    float mx = fmaxf(fmaxf(m0, m1), fmaxf(m2, m3));
    float sum = 0.f;
    for (j = lo; j < hi; ++j) {
        float pe = __expf(p[(size_t)j * H + hh] - mx);
        p[(size_t)j * H + hh] = pe;
        sum += pe;
    }
    rden[gid] = 1.f / (sum + 1e-16f);
}

// ---------------- gather-aggregate (8 heads, 512 ch) + bias + ELU -> bf16 out (R7-proven) ------
// R12: output stores are non-temporal -> 50MB write stream no longer evicts the randomly
// re-read 51MB h array from L2 during the gather.
__global__ __launch_bounds__(256) void agg8_kernel(const unsigned short* __restrict__ h,
                                                   const float* __restrict__ p,
                                                   const int* __restrict__ rowptr,
                                                   const int* __restrict__ srcs,
                                                   const float* __restrict__ rden,
                                                   const float* __restrict__ bias,
                                                   unsigned short* __restrict__ out) {
    int n = blockIdx.x;
    int t = threadIdx.x;           // pair index: channels 2t, 2t+1 (same head)
    int hh = t >> 5;               // (2t)/64
    int lo = rowptr[n], hi = rowptr[n + 1];
    float rd = rden[n * 8 + hh];
    float a0 = 0.f, a1 = 0.f, b0 = 0.f, b1 = 0.f;
    float c0 = 0.f, c1 = 0.f, d0 = 0.f, d1 = 0.f;
    int j = lo;
    for (; j + 4 <= hi; j += 4) {
        int s0 = srcs[j], s1 = srcs[j + 1], s2 = srcs[j + 2], s3 = srcs[j + 3];
        unsigned v0 = *(const unsigned*)(h + (size_t)s0 * 512 + 2 * t);
        unsigned v1 = *(const unsigned*)(h + (size_t)s1 * 512 + 2 * t);
        unsigned v2 = *(const unsigned*)(h + (size_t)s2 * 512 + 2 * t);
        unsigned v3 = *(const unsigned*)(h + (size_t)s3 * 512 + 2 * t);
        float p0 = p[(size_t)j * 8 + hh];
        float p1 = p[(size_t)(j + 1) * 8 + hh];
        float p2 = p[(size_t)(j + 2) * 8 + hh];
        float p3 = p[(size_t)(j + 3) * 8 + hh];
        a0 = fmaf(p0, bf2f((unsigned short)(v0 & 0xffff)), a0);
        a1 = fmaf(p0, bf2f((unsigned short)(v0 >> 16)), a1);
        b0 = fmaf(p1, bf2f((unsigned short)(v1 & 0xffff)), b0);
        b1 = fmaf(p1, bf2f((unsigned short)(v1 >> 16)), b1);
        c0 = fmaf(p2, bf2f((unsigned short)(v2 & 0xffff)), c0);
        c1 = fmaf(p2, bf2f((unsigned short)(v2 >> 16)), c1);
        d0 = fmaf(p3, bf2f((unsigned short)(v3 & 0xffff)), d0);
        d1 = fmaf(p3, bf2f((unsigned short)(v3 >> 16)), d1);
    }
    for (; j < hi; ++j) {
        int s = srcs[j];
        unsigned v = *(const unsigned*)(h + (size_t)s * 512 + 2 * t);
        float pj = p[(size_t)j * 8 + hh];
        a0 = fmaf(pj, bf2f((unsigned short)(v & 0xffff)), a0);
        a1 = fmaf(pj, bf2f((unsigned short)(v >> 16)), a1);
    }
    float s0 = (a0 + b0) + (c0 + d0);
    float s1 = (a1 + b1) + (c1 + d1);
    float2 bv = *(const float2*)(bias + 2 * t);
    float v0 = elu1(s0 * rd + bv.x);
    float v1 = elu1(s1 * rd + bv.y);
    unsigned pack = (unsigned)f2bf(v0) | ((unsigned)f2bf(v1) << 16);
    __builtin_nontemporal_store(pack, (unsigned*)(out + (size_t)n * 512 + 2 * t));
}

// ---------------- fused gather-aggregate (1 head) + bias + ELU + classifier -> sigmoid ---------
// R12: the 64-thread block holds the full output row (1 ch/lane); wave-reduce v*Wc directly
// and write sigmoid(logit) -> d_out. Deletes cls kernel + the g3 12.8MB round-trip.
__global__ __launch_bounds__(64) void agg1cls_kernel(const unsigned short* __restrict__ h,
                                                     const float* __restrict__ p,
                                                     const int* __restrict__ rowptr,
                                                     const int* __restrict__ srcs,
                                                     const float* __restrict__ rden,
                                                     const float* __restrict__ bias,
                                                     const float* __restrict__ Wc,
                                                     const float* __restrict__ bc,
                                                     float* __restrict__ out) {
    int n = blockIdx.x;
    int t = threadIdx.x;
    int lo = rowptr[n], hi = rowptr[n + 1];
    float rd = rden[n];
    float a = 0.f, b = 0.f, c = 0.f, d = 0.f;
    int j = lo;
    for (; j + 4 <= hi; j += 4) {
        int s0 = srcs[j], s1 = srcs[j + 1], s2 = srcs[j + 2], s3 = srcs[j + 3];
        float h0 = bf2f(h[(size_t)s0 * 64 + t]);
        float h1 = bf2f(h[(size_t)s1 * 64 + t]);
        float h2 = bf2f(h[(size_t)s2 * 64 + t]);
        float h3 = bf2f(h[(size_t)s3 * 64 + t]);
        a = fmaf(p[j], h0, a);
        b = fmaf(p[j + 1], h1, b);
        c = fmaf(p[j + 2], h2, c);
        d = fmaf(p[j + 3], h3, d);
    }
    for (; j < hi; ++j) {
        a = fmaf(p[j], bf2f(h[(size_t)srcs[j] * 64 + t]), a);
    }
    float acc = (a + b) + (c + d);
    float v = elu1(acc * rd + bias[t]);
    float prod = v * Wc[t];
#pragma unroll
    for (int off = 32; off >= 1; off >>= 1) prod += __shfl_down(prod, off);
    if (t == 0) out[n] = 1.f / (1.f + __expf(-(prod + bc[0])));
}

extern "C" void kernel_launch(void* const* d_in, const int* in_sizes, int n_in,
                              void* d_out, int out_size, void* d_ws, size_t ws_size,
                              hipStream_t stream) {
    const float* x   = (const float*)d_in[0];
    const int*   ei  = (const int*)d_in[1];
    const int* src_row = ei;
    const int* dst_row = ei + N_EDGES;
    const float* W1  = (const float*)d_in[2];
    const float* as1 = (const float*)d_in[3];
    const float* ad1 = (const float*)d_in[4];
    const float* b1  = (const float*)d_in[5];
    const float* W2  = (const float*)d_in[6];
    const float* as2 = (const float*)d_in[7];
    const float* ad2 = (const float*)d_in[8];
    const float* b2  = (const float*)d_in[9];
    const float* W3  = (const float*)d_in[10];
    const float* as3 = (const float*)d_in[11];
    const float* ad3 = (const float*)d_in[12];
    const float* b3  = (const float*)d_in[13];
    const float* Wc  = (const float*)d_in[14];
    const float* bc  = (const float*)d_in[15];

    char* w = (char*)d_ws;
    auto alloc = [&](size_t bytes) -> void* {
        void* ptr = (void*)w;
        w += (bytes + 255) & ~(size_t)255;
        return ptr;
    };
    int*   deg    = (int*)alloc((size_t)N_NODES * 4);
    int*   rowptr = (int*)alloc((size_t)(N_NODES + 1) * 4);
    int*   cursor = (int*)alloc((size_t)N_NODES * 4);
    int*   srcs   = (int*)alloc((size_t)E_TOT * 4);
    int*   psum   = (int*)alloc((size_t)NBLK * 4);
    float* pbuf   = (float*)alloc((size_t)E_TOT * HEADS * 4);
    float* ssrc   = (float*)alloc((size_t)N_NODES * HEADS * 4);
    float* sdst   = (float*)alloc((size_t)N_NODES * HEADS * 4);
    float* rden   = (float*)alloc((size_t)N_NODES * HEADS * 4);
    unsigned short* hbf = (unsigned short*)alloc((size_t)N_NODES * HC * 2);  // bf16 h (GEMM out)
    unsigned short* gbf = (unsigned short*)alloc((size_t)N_NODES * HC * 2);  // agg out (bf16)
    unsigned short* w2t = (unsigned short*)alloc((size_t)512 * 512 * 2);
    unsigned short* w3t = (unsigned short*)alloc((size_t)64 * 512 * 2);

    hipMemsetAsync(deg, 0, (size_t)N_NODES * 4, stream);

    const int EB = (E_TOT + 255) / 256;
    hist_kernel<<<EB, 256, 0, stream>>>(dst_row, deg);
    deg_partial_kernel<<<NBLK, 256, 0, stream>>>(deg, psum);
    scan_partial_kernel<<<1, 256, 0, stream>>>(psum);
    rowptr_kernel<<<NBLK, 256, 0, stream>>>(deg, psum, rowptr, cursor);
    scatter_kernel<<<EB, 256, 0, stream>>>(src_row, dst_row, cursor, srcs);

    // weight transpose (bf16, tiny; once per call)
    wtrans_kernel<512><<<(512 * 512 + 255) / 256, 256, 0, stream>>>(W2, w2t);
    wtrans_kernel<64><<<(512 * 64 + 255) / 256, 256, 0, stream>>>(W3, w3t);

    const int NHB = (N_NODES * HEADS + 255) / 256;
    const int NB  = (N_NODES + 255) / 256;
    const int MB128 = (N_NODES + 127) / 128;                 // 391
    const int G2 = ((MB128 + 7) / 8) * 32;                   // 49 groups x (4x * 8y) = 1568
    const int MB64 = (N_NODES + 63) / 64;                    // 782
    const int G3 = ((MB64 + 7) / 8) * 8;                     // 784

    // ---- layer 1: x[N,5] -> hbf[N,512] -> attn -> gbf ----
    gemm5_kernel<<<(N_NODES * HC + 255) / 256, 256, 0, stream>>>(x, W1, hbf);
    score_kernel<8><<<NHB, 256, 0, stream>>>(hbf, as1, ad1, ssrc, sdst);
    softmax_kernel<8><<<NHB, 256, 0, stream>>>(rowptr, srcs, ssrc, sdst, pbuf, rden);
    agg8_kernel<<<N_NODES, 256, 0, stream>>>(hbf, pbuf, rowptr, srcs, rden, b1, gbf);

    // ---- layer 2: gbf @ W2 (bf16 MFMA, y-grouped XCD swizzle) -> hbf -> attn -> gbf ----
    gemm_mfma<128, 128, 2, 2, 4><<<G2, 256, 0, stream>>>(gbf, w2t, hbf, N_NODES, 512, 511);
    score_kernel<8><<<NHB, 256, 0, stream>>>(hbf, as2, ad2, ssrc, sdst);
    softmax_kernel<8><<<NHB, 256, 0, stream>>>(rowptr, srcs, ssrc, sdst, pbuf, rden);
    agg8_kernel<<<N_NODES, 256, 0, stream>>>(hbf, pbuf, rowptr, srcs, rden, b2, gbf);

    // ---- layer 3: gbf @ W3 (BM=64) -> hbf[N,64] -> attn (1 head) -> fused agg+cls -> d_out ----
    gemm_mfma<64, 64, 2, 1, 1><<<G3, 128, 0, stream>>>(gbf, w3t, hbf, N_NODES, 64, 63);
    score_kernel<1><<<NB, 256, 0, stream>>>(hbf, as3, ad3, ssrc, sdst);
    softmax_kernel<1><<<NB, 256, 0, stream>>>(rowptr, srcs, ssrc, sdst, pbuf, rden);
    agg1cls_kernel<<<N_NODES, 64, 0, stream>>>(hbf, pbuf, rowptr, srcs, rden, b3, Wc, bc,
                                               (float*)d_out);
}

// Round 13
// 503.090 us; speedup vs baseline: 1.0642x; 1.0642x over previous
//
#include <hip/hip_runtime.h>
#include <hip/hip_bf16.h>
#include <math.h>

#define N_NODES 50000
#define N_EDGES 400000
#define E_TOT   (N_EDGES + N_NODES)   // self loops appended
#define HEADS   8
#define HID     64
#define HC      (HEADS * HID)         // 512
#define NBLK    ((N_NODES + 255) / 256)  // 196 scan blocks

typedef __attribute__((ext_vector_type(8))) short bf16x8;  // 8 bf16 (4 VGPRs)
typedef __attribute__((ext_vector_type(4))) float f32x4;

__device__ __forceinline__ float elu1(float x) { return x > 0.f ? x : __expf(x) - 1.f; }

// round-to-nearest-even fp32 -> bf16 (raw ushort)
__device__ __forceinline__ unsigned short f2bf(float x) {
    unsigned u = __float_as_uint(x);
    unsigned r = (u + 0x7FFFu + ((u >> 16) & 1u)) >> 16;
    return (unsigned short)r;
}
__device__ __forceinline__ float bf2f(unsigned short h) {
    return __uint_as_float(((unsigned)h) << 16);
}

// ---------------- CSR build (by dst) ----------------
__global__ void hist_kernel(const int* __restrict__ dst, int* __restrict__ deg) {
    int e = blockIdx.x * blockDim.x + threadIdx.x;
    if (e >= E_TOT) return;
    int d = (e < N_EDGES) ? dst[e] : (e - N_EDGES);
    atomicAdd(&deg[d], 1);
}

__global__ __launch_bounds__(256) void deg_partial_kernel(const int* __restrict__ deg,
                                                          int* __restrict__ psum) {
    __shared__ int sm[256];
    int t = threadIdx.x;
    int idx = blockIdx.x * 256 + t;
    int v = (idx < N_NODES) ? deg[idx] : 0;
    sm[t] = v;
    __syncthreads();
    for (int off = 128; off >= 1; off >>= 1) {
        if (t < off) sm[t] += sm[t + off];
        __syncthreads();
    }
    if (t == 0) psum[blockIdx.x] = sm[0];
}

__global__ __launch_bounds__(256) void scan_partial_kernel(int* __restrict__ psum) {
    __shared__ int sm[256];
    int t = threadIdx.x;
    int v = (t < NBLK) ? psum[t] : 0;
    sm[t] = v;
    __syncthreads();
    for (int off = 1; off < 256; off <<= 1) {
        int add = (t >= off) ? sm[t - off] : 0;
        __syncthreads();
        sm[t] += add;
        __syncthreads();
    }
    if (t < NBLK) psum[t] = sm[t] - v;  // exclusive
}

__global__ __launch_bounds__(256) void rowptr_kernel(const int* __restrict__ deg,
                                                     const int* __restrict__ psum,
                                                     int* __restrict__ rowptr,
                                                     int* __restrict__ cursor) {
    __shared__ int sm[256];
    int t = threadIdx.x;
    int idx = blockIdx.x * 256 + t;
    int v = (idx < N_NODES) ? deg[idx] : 0;
    sm[t] = v;
    __syncthreads();
    for (int off = 1; off < 256; off <<= 1) {
        int add = (t >= off) ? sm[t - off] : 0;
        __syncthreads();
        sm[t] += add;
        __syncthreads();
    }
    if (idx < N_NODES) {
        int r = psum[blockIdx.x] + sm[t] - v;  // exclusive
        rowptr[idx] = r;
        cursor[idx] = r;
    }
    if (idx == 0) rowptr[N_NODES] = E_TOT;
}

__global__ void scatter_kernel(const int* __restrict__ srcrow, const int* __restrict__ dstrow,
                               int* __restrict__ cursor, int* __restrict__ src_sorted) {
    int e = blockIdx.x * blockDim.x + threadIdx.x;
    if (e >= E_TOT) return;
    int s, d;
    if (e < N_EDGES) { s = srcrow[e]; d = dstrow[e]; }
    else             { s = d = e - N_EDGES; }
    int pos = atomicAdd(&cursor[d], 1);
    src_sorted[pos] = s;
}

// ---------------- Layer 1 GEMM: [N,5] @ [5,512] -> bf16 h ----------------
__global__ void gemm5_kernel(const float* __restrict__ x, const float* __restrict__ W,
                             unsigned short* __restrict__ h) {
    int gid = blockIdx.x * blockDim.x + threadIdx.x;
    if (gid >= N_NODES * HC) return;
    int n = gid >> 9, c = gid & 511;
    const float* xr = x + n * 5;
    float acc = xr[0] * W[c] + xr[1] * W[512 + c] + xr[2] * W[1024 + c] +
                xr[3] * W[1536 + c] + xr[4] * W[2048 + c];
    h[gid] = f2bf(acc);
}

// ---------------- W -> W^T bf16: W[512][NCOL] -> Wt[NCOL][512] ----------------
template <int NCOL>
__global__ void wtrans_kernel(const float* __restrict__ W, unsigned short* __restrict__ hi) {
    int idx = blockIdx.x * 256 + threadIdx.x;
    if (idx >= 512 * NCOL) return;
    int k = idx / NCOL, n = idx % NCOL;
    hi[(size_t)n * 512 + k] = f2bf(W[idx]);
}

// ---------------- bf16 MFMA GEMM + fused score epilogue ----------------
// LDS rows of 64B; 16B-slot p holds k-chunk g = p ^ ((row>>1)&3) (zero-conflict, R5-measured).
// Full 128B-line staging per row via back-to-back half-chunks (R6).
template <int ROWS, int NW>
__device__ __forceinline__ void stage_pair(const unsigned short* __restrict__ src, int row0,
                                           int maxRow, int k0, char* lds0, char* lds1,
                                           int wave, int lane) {
    constexpr int CHUNKS = ROWS / 16;  // 1KB chunks (16 rows x 64B) per half
    for (int c = wave; c < CHUNKS; c += NW) {
        int r = c * 16 + (lane >> 2);
        int p = lane & 3;
        int g = p ^ ((r >> 1) & 3);
        int gr = row0 + r;
        if (gr > maxRow) gr = maxRow;  // tail clamp; result write-guarded
        const unsigned short* gp = src + (size_t)gr * 512 + k0 + g * 8;
        __builtin_amdgcn_global_load_lds((const __attribute__((address_space(1))) void*)gp,
                                         (__attribute__((address_space(3))) void*)(lds0 + c * 1024),
                                         16, 0, 0);
        __builtin_amdgcn_global_load_lds((const __attribute__((address_space(1))) void*)(gp + 32),
                                         (__attribute__((address_space(3))) void*)(lds1 + c * 1024),
                                         16, 0, 0);
    }
}

// 1D grid, y-grouped XCD swizzle (T1): blocks sharing an A panel (same by, bx=0..GX-1)
// get wg % 8 == by % 8 -> same XCD -> A-panel L2 reuse.
// R13: SCORE epilogue — wave wc covers exactly 64 cols = one head (BN/WN==64), so s_src/s_dst
// are computed from the fp32 acc in-register (xor-reduce over lane&15 per m89 layout),
// deleting the separate score kernels and their h re-reads.
template <int BM, int BN, int WM, int WN, int GX, int SH, bool SCORE>
__global__ __launch_bounds__(WM * WN * 64) void gemm_mfma(
    const unsigned short* __restrict__ A, const unsigned short* __restrict__ B,
    unsigned short* __restrict__ C,
    const float* __restrict__ asrc, const float* __restrict__ adst,
    float* __restrict__ ssrc, float* __restrict__ sdst,
    int M, int Nout, int maxRowB) {
    constexpr int NW = WM * WN;
    constexpr int MI = BM / (16 * WM);
    constexpr int NI = BN / (16 * WN);
    static_assert(!SCORE || NI * 16 == 64, "score epilogue needs 64 cols per wave");
    constexpr int ABYTES = BM * 64;
    constexpr int BBYTES = BN * 64;
    constexpr int GRPS = GX * 8;
    __shared__ __attribute__((aligned(16))) char lds[(ABYTES + BBYTES) * 2];
    char* const pA0 = lds;
    char* const pA1 = pA0 + ABYTES;
    char* const pB0 = pA1 + ABYTES;
    char* const pB1 = pB0 + BBYTES;

    const int wg = blockIdx.x;
    const int bx = (wg % GRPS) >> 3;
    const int by = (wg / GRPS) * 8 + (wg & 7);
    if (by * BM >= M) return;  // whole block exits before any barrier
    const int m0 = by * BM, n0 = bx * BN;

    const int t = threadIdx.x, lane = t & 63, wave = t >> 6;
    const int wr = wave / WN, wc = wave % WN;

    int offA[MI], offB[NI];
#pragma unroll
    for (int s = 0; s < MI; ++s) {
        int rA = (wr * MI + s) * 16 + (lane & 15);
        offA[s] = rA * 64 + ((((lane >> 4) ^ ((rA >> 1) & 3))) << 4);
    }
#pragma unroll
    for (int s = 0; s < NI; ++s) {
        int rB = (wc * NI + s) * 16 + (lane & 15);
        offB[s] = rB * 64 + ((((lane >> 4) ^ ((rB >> 1) & 3))) << 4);
    }

    f32x4 acc[MI][NI] = {};

    for (int k0 = 0; k0 < 512; k0 += 64) {
        stage_pair<BM, NW>(A, m0, M - 1,   k0, pA0, pA1, wave, lane);
        stage_pair<BN, NW>(B, n0, maxRowB, k0, pB0, pB1, wave, lane);
        __syncthreads();  // compiler drains vmcnt before barrier -> LDS valid

#pragma unroll
        for (int half = 0; half < 2; ++half) {
            const char* cA = half ? pA1 : pA0;
            const char* cB = half ? pB1 : pB0;
            bf16x8 av[MI], bv[NI];
#pragma unroll
            for (int s = 0; s < MI; ++s) av[s] = *(const bf16x8*)(cA + offA[s]);
#pragma unroll
            for (int s = 0; s < NI; ++s) bv[s] = *(const bf16x8*)(cB + offB[s]);
#pragma unroll
            for (int i = 0; i < MI; ++i)
#pragma unroll
                for (int j = 0; j < NI; ++j)
                    acc[i][j] = __builtin_amdgcn_mfma_f32_16x16x32_bf16(av[i], bv[j], acc[i][j], 0, 0, 0);
        }
        __syncthreads();
    }

    // C/D layout (m89-verified): col = lane&15, row = (lane>>4)*4 + reg
#pragma unroll
    for (int i = 0; i < MI; ++i) {
        int row = m0 + (wr * MI + i) * 16 + ((lane >> 4) << 2);
#pragma unroll
        for (int j = 0; j < NI; ++j) {
            int col = n0 + (wc * NI + j) * 16 + (lane & 15);
            f32x4 v = acc[i][j];
#pragma unroll
            for (int r = 0; r < 4; ++r) {
                if (row + r < M) C[(size_t)(row + r) * Nout + col] = f2bf(v[r]);
            }
        }
    }

    if constexpr (SCORE) {
        const int head = n0 / 64 + wc;   // wave's 64 columns == this head
        float aS[NI], aD[NI];
#pragma unroll
        for (int j = 0; j < NI; ++j) {
            int cl = j * 16 + (lane & 15);
            aS[j] = asrc[head * 64 + cl];
            aD[j] = adst[head * 64 + cl];
        }
        float Ps[MI][4], Pd[MI][4];
#pragma unroll
        for (int i = 0; i < MI; ++i)
#pragma unroll
            for (int r = 0; r < 4; ++r) { Ps[i][r] = 0.f; Pd[i][r] = 0.f; }
#pragma unroll
        for (int i = 0; i < MI; ++i)
#pragma unroll
            for (int j = 0; j < NI; ++j)
#pragma unroll
                for (int r = 0; r < 4; ++r) {
                    Ps[i][r] = fmaf(acc[i][j][r], aS[j], Ps[i][r]);
                    Pd[i][r] = fmaf(acc[i][j][r], aD[j], Pd[i][r]);
                }
        // reduce over the 16 lanes sharing lane>>4 (cols) -> every lane holds full row sums
#pragma unroll
        for (int step = 1; step <= 8; step <<= 1) {
#pragma unroll
            for (int i = 0; i < MI; ++i)
#pragma unroll
                for (int r = 0; r < 4; ++r) {
                    Ps[i][r] += __shfl_xor(Ps[i][r], step, 64);
                    Pd[i][r] += __shfl_xor(Pd[i][r], step, 64);
                }
        }
        int idx = lane & 15, g = lane >> 4;
        if (idx < MI * 4) {
            float vs = 0.f, vd = 0.f;
#pragma unroll
            for (int i = 0; i < MI; ++i)
#pragma unroll
                for (int r = 0; r < 4; ++r) {
                    bool sel = (idx == i * 4 + r);
                    vs = sel ? Ps[i][r] : vs;
                    vd = sel ? Pd[i][r] : vd;
                }
            int ii = idx >> 2, rr = idx & 3;
            int row = m0 + (wr * MI + ii) * 16 + g * 4 + rr;
            if (row < M) {
                ssrc[(size_t)row * SH + head] = vs;
                sdst[(size_t)row * SH + head] = vd;
            }
        }
    }
}

// ---------------- attention scores from bf16 h (layer 1 only) ----------------
template <int H>
__global__ void score_kernel(const unsigned short* __restrict__ h,
                             const float* __restrict__ a_src, const float* __restrict__ a_dst,
                             float* __restrict__ ssrc, float* __restrict__ sdst) {
    int gid = blockIdx.x * blockDim.x + threadIdx.x;
    if (gid >= N_NODES * H) return;
    int n = gid / H, hh = gid % H;
    const unsigned short* hp = h + (size_t)n * (H * 64) + hh * 64;
    const float* asp = a_src + hh * 64;
    const float* adp = a_dst + hh * 64;
    float s1 = 0.f, s2 = 0.f;
#pragma unroll
    for (int k = 0; k < 64; k += 8) {
        uint4 hv = *(const uint4*)(hp + k);
        const unsigned u[4] = {hv.x, hv.y, hv.z, hv.w};
#pragma unroll
        for (int q = 0; q < 4; ++q) {
            float f0 = bf2f((unsigned short)(u[q] & 0xffff));
            float f1 = bf2f((unsigned short)(u[q] >> 16));
            s1 = fmaf(f0, asp[k + 2 * q], fmaf(f1, asp[k + 2 * q + 1], s1));
            s2 = fmaf(f0, adp[k + 2 * q], fmaf(f1, adp[k + 2 * q + 1], s2));
        }
    }
    ssrc[gid] = s1;
    sdst[gid] = s2;
}

// ---------------- per-(dst,head) softmax (4-wide gather pipeline, R7-proven) ----------------
template <int H>
__global__ void softmax_kernel(const int* __restrict__ rowptr, const int* __restrict__ srcs,
                               const float* __restrict__ ssrc, const float* __restrict__ sdst,
                               float* __restrict__ p, float* __restrict__ rden) {
    int gid = blockIdx.x * blockDim.x + threadIdx.x;
    if (gid >= N_NODES * H) return;
    int n = gid / H, hh = gid % H;
    int lo = rowptr[n], hi = rowptr[n + 1];
    float sd = sdst[gid];
    float m0 = -3.4e38f, m1 = -3.4e38f, m2 = -3.4e38f, m3 = -3.4e38f;
    int j = lo;
    for (; j + 4 <= hi; j += 4) {
        int s0 = srcs[j], s1 = srcs[j + 1], s2 = srcs[j + 2], s3 = srcs[j + 3];
        float v0 = ssrc[s0 * H + hh] + sd;
        float v1 = ssrc[s1 * H + hh] + sd;
        float v2 = ssrc[s2 * H + hh] + sd;
        float v3 = ssrc[s3 * H + hh] + sd;
        v0 = v0 > 0.f ? v0 : 0.2f * v0;
        v1 = v1 > 0.f ? v1 : 0.2f * v1;
        v2 = v2 > 0.f ? v2 : 0.2f * v2;
        v3 = v3 > 0.f ? v3 : 0.2f * v3;
        p[(size_t)j * H + hh] = v0;
        p[(size_t)(j + 1) * H + hh] = v1;
        p[(size_t)(j + 2) * H + hh] = v2;
        p[(size_t)(j + 3) * H + hh] = v3;
        m0 = fmaxf(m0, v0); m1 = fmaxf(m1, v1);
        m2 = fmaxf(m2, v2); m3 = fmaxf(m3, v3);
    }
    for (; j < hi; ++j) {
        float v = ssrc[srcs[j] * H + hh] + sd;
        v = v > 0.f ? v : 0.2f * v;
        p[(size_t)j * H + hh] = v;
        m0 = fmaxf(m0, v);
    }
    float mx = fmaxf(fmaxf(m0, m1), fmaxf(m2, m3));
    float sum = 0.f;
    for (j = lo; j < hi; ++j) {
        float pe = __expf(p[(size_t)j * H + hh] - mx);
        p[(size_t)j * H + hh] = pe;
        sum += pe;
    }
    rden[gid] = 1.f / (sum + 1e-16f);
}

// ---------------- gather-aggregate (8 heads, 512 ch) + bias + ELU -> bf16 out (R7-proven) ------
__global__ __launch_bounds__(256) void agg8_kernel(const unsigned short* __restrict__ h,
                                                   const float* __restrict__ p,
                                                   const int* __restrict__ rowptr,
                                                   const int* __restrict__ srcs,
                                                   const float* __restrict__ rden,
                                                   const float* __restrict__ bias,
                                                   unsigned short* __restrict__ out) {
    int n = blockIdx.x;
    int t = threadIdx.x;           // pair index: channels 2t, 2t+1 (same head)
    int hh = t >> 5;               // (2t)/64
    int lo = rowptr[n], hi = rowptr[n + 1];
    float rd = rden[n * 8 + hh];
    float a0 = 0.f, a1 = 0.f, b0 = 0.f, b1 = 0.f;
    float c0 = 0.f, c1 = 0.f, d0 = 0.f, d1 = 0.f;
    int j = lo;
    for (; j + 4 <= hi; j += 4) {
        int s0 = srcs[j], s1 = srcs[j + 1], s2 = srcs[j + 2], s3 = srcs[j + 3];
        unsigned v0 = *(const unsigned*)(h + (size_t)s0 * 512 + 2 * t);
        unsigned v1 = *(const unsigned*)(h + (size_t)s1 * 512 + 2 * t);
        unsigned v2 = *(const unsigned*)(h + (size_t)s2 * 512 + 2 * t);
        unsigned v3 = *(const unsigned*)(h + (size_t)s3 * 512 + 2 * t);
        float p0 = p[(size_t)j * 8 + hh];
        float p1 = p[(size_t)(j + 1) * 8 + hh];
        float p2 = p[(size_t)(j + 2) * 8 + hh];
        float p3 = p[(size_t)(j + 3) * 8 + hh];
        a0 = fmaf(p0, bf2f((unsigned short)(v0 & 0xffff)), a0);
        a1 = fmaf(p0, bf2f((unsigned short)(v0 >> 16)), a1);
        b0 = fmaf(p1, bf2f((unsigned short)(v1 & 0xffff)), b0);
        b1 = fmaf(p1, bf2f((unsigned short)(v1 >> 16)), b1);
        c0 = fmaf(p2, bf2f((unsigned short)(v2 & 0xffff)), c0);
        c1 = fmaf(p2, bf2f((unsigned short)(v2 >> 16)), c1);
        d0 = fmaf(p3, bf2f((unsigned short)(v3 & 0xffff)), d0);
        d1 = fmaf(p3, bf2f((unsigned short)(v3 >> 16)), d1);
    }
    for (; j < hi; ++j) {
        int s = srcs[j];
        unsigned v = *(const unsigned*)(h + (size_t)s * 512 + 2 * t);
        float pj = p[(size_t)j * 8 + hh];
        a0 = fmaf(pj, bf2f((unsigned short)(v & 0xffff)), a0);
        a1 = fmaf(pj, bf2f((unsigned short)(v >> 16)), a1);
    }
    float s0 = (a0 + b0) + (c0 + d0);
    float s1 = (a1 + b1) + (c1 + d1);
    float2 bv = *(const float2*)(bias + 2 * t);
    float v0 = elu1(s0 * rd + bv.x);
    float v1 = elu1(s1 * rd + bv.y);
    unsigned pack = (unsigned)f2bf(v0) | ((unsigned)f2bf(v1) << 16);
    *(unsigned*)(out + (size_t)n * 512 + 2 * t) = pack;
}

// ---------------- fused gather-aggregate (1 head) + bias + ELU + classifier -> sigmoid ---------
__global__ __launch_bounds__(64) void agg1cls_kernel(const unsigned short* __restrict__ h,
                                                     const float* __restrict__ p,
                                                     const int* __restrict__ rowptr,
                                                     const int* __restrict__ srcs,
                                                     const float* __restrict__ rden,
                                                     const float* __restrict__ bias,
                                                     const float* __restrict__ Wc,
                                                     const float* __restrict__ bc,
                                                     float* __restrict__ out) {
    int n = blockIdx.x;
    int t = threadIdx.x;
    int lo = rowptr[n], hi = rowptr[n + 1];
    float rd = rden[n];
    float a = 0.f, b = 0.f, c = 0.f, d = 0.f;
    int j = lo;
    for (; j + 4 <= hi; j += 4) {
        int s0 = srcs[j], s1 = srcs[j + 1], s2 = srcs[j + 2], s3 = srcs[j + 3];
        float h0 = bf2f(h[(size_t)s0 * 64 + t]);
        float h1 = bf2f(h[(size_t)s1 * 64 + t]);
        float h2 = bf2f(h[(size_t)s2 * 64 + t]);
        float h3 = bf2f(h[(size_t)s3 * 64 + t]);
        a = fmaf(p[j], h0, a);
        b = fmaf(p[j + 1], h1, b);
        c = fmaf(p[j + 2], h2, c);
        d = fmaf(p[j + 3], h3, d);
    }
    for (; j < hi; ++j) {
        a = fmaf(p[j], bf2f(h[(size_t)srcs[j] * 64 + t]), a);
    }
    float acc = (a + b) + (c + d);
    float v = elu1(acc * rd + bias[t]);
    float prod = v * Wc[t];
#pragma unroll
    for (int off = 32; off >= 1; off >>= 1) prod += __shfl_down(prod, off);
    if (t == 0) out[n] = 1.f / (1.f + __expf(-(prod + bc[0])));
}

extern "C" void kernel_launch(void* const* d_in, const int* in_sizes, int n_in,
                              void* d_out, int out_size, void* d_ws, size_t ws_size,
                              hipStream_t stream) {
    const float* x   = (const float*)d_in[0];
    const int*   ei  = (const int*)d_in[1];
    const int* src_row = ei;
    const int* dst_row = ei + N_EDGES;
    const float* W1  = (const float*)d_in[2];
    const float* as1 = (const float*)d_in[3];
    const float* ad1 = (const float*)d_in[4];
    const float* b1  = (const float*)d_in[5];
    const float* W2  = (const float*)d_in[6];
    const float* as2 = (const float*)d_in[7];
    const float* ad2 = (const float*)d_in[8];
    const float* b2  = (const float*)d_in[9];
    const float* W3  = (const float*)d_in[10];
    const float* as3 = (const float*)d_in[11];
    const float* ad3 = (const float*)d_in[12];
    const float* b3  = (const float*)d_in[13];
    const float* Wc  = (const float*)d_in[14];
    const float* bc  = (const float*)d_in[15];

    char* w = (char*)d_ws;
    auto alloc = [&](size_t bytes) -> void* {
        void* ptr = (void*)w;
        w += (bytes + 255) & ~(size_t)255;
        return ptr;
    };
    int*   deg    = (int*)alloc((size_t)N_NODES * 4);
    int*   rowptr = (int*)alloc((size_t)(N_NODES + 1) * 4);
    int*   cursor = (int*)alloc((size_t)N_NODES * 4);
    int*   srcs   = (int*)alloc((size_t)E_TOT * 4);
    int*   psum   = (int*)alloc((size_t)NBLK * 4);
    float* pbuf   = (float*)alloc((size_t)E_TOT * HEADS * 4);
    float* ssrc   = (float*)alloc((size_t)N_NODES * HEADS * 4);
    float* sdst   = (float*)alloc((size_t)N_NODES * HEADS * 4);
    float* rden   = (float*)alloc((size_t)N_NODES * HEADS * 4);
    unsigned short* hbf = (unsigned short*)alloc((size_t)N_NODES * HC * 2);  // bf16 h (GEMM out)
    unsigned short* gbf = (unsigned short*)alloc((size_t)N_NODES * HC * 2);  // agg out (bf16)
    unsigned short* w2t = (unsigned short*)alloc((size_t)512 * 512 * 2);
    unsigned short* w3t = (unsigned short*)alloc((size_t)64 * 512 * 2);

    hipMemsetAsync(deg, 0, (size_t)N_NODES * 4, stream);

    const int EB = (E_TOT + 255) / 256;
    hist_kernel<<<EB, 256, 0, stream>>>(dst_row, deg);
    deg_partial_kernel<<<NBLK, 256, 0, stream>>>(deg, psum);
    scan_partial_kernel<<<1, 256, 0, stream>>>(psum);
    rowptr_kernel<<<NBLK, 256, 0, stream>>>(deg, psum, rowptr, cursor);
    scatter_kernel<<<EB, 256, 0, stream>>>(src_row, dst_row, cursor, srcs);

    // weight transpose (bf16, tiny; once per call)
    wtrans_kernel<512><<<(512 * 512 + 255) / 256, 256, 0, stream>>>(W2, w2t);
    wtrans_kernel<64><<<(512 * 64 + 255) / 256, 256, 0, stream>>>(W3, w3t);

    const int NHB = (N_NODES * HEADS + 255) / 256;
    const int NB  = (N_NODES + 255) / 256;
    const int MB128 = (N_NODES + 127) / 128;                 // 391
    const int G2 = ((MB128 + 7) / 8) * 32;                   // 49 groups x (4x * 8y) = 1568
    const int MB64 = (N_NODES + 63) / 64;                    // 782
    const int G3 = ((MB64 + 7) / 8) * 8;                     // 784

    // ---- layer 1: x[N,5] -> hbf[N,512] -> attn -> gbf ----
    gemm5_kernel<<<(N_NODES * HC + 255) / 256, 256, 0, stream>>>(x, W1, hbf);
    score_kernel<8><<<NHB, 256, 0, stream>>>(hbf, as1, ad1, ssrc, sdst);
    softmax_kernel<8><<<NHB, 256, 0, stream>>>(rowptr, srcs, ssrc, sdst, pbuf, rden);
    agg8_kernel<<<N_NODES, 256, 0, stream>>>(hbf, pbuf, rowptr, srcs, rden, b1, gbf);

    // ---- layer 2: gbf @ W2 (bf16 MFMA + fused score) -> hbf, ssrc/sdst -> softmax -> agg ----
    gemm_mfma<128, 128, 2, 2, 4, 8, true><<<G2, 256, 0, stream>>>(
        gbf, w2t, hbf, as2, ad2, ssrc, sdst, N_NODES, 512, 511);
    softmax_kernel<8><<<NHB, 256, 0, stream>>>(rowptr, srcs, ssrc, sdst, pbuf, rden);
    agg8_kernel<<<N_NODES, 256, 0, stream>>>(hbf, pbuf, rowptr, srcs, rden, b2, gbf);

    // ---- layer 3: gbf @ W3 (BM=64, fused score, 1 head) -> softmax -> fused agg+cls ----
    gemm_mfma<64, 64, 2, 1, 1, 1, true><<<G3, 128, 0, stream>>>(
        gbf, w3t, hbf, as3, ad3, ssrc, sdst, N_NODES, 64, 63);
    softmax_kernel<1><<<NB, 256, 0, stream>>>(rowptr, srcs, ssrc, sdst, pbuf, rden);
    agg1cls_kernel<<<N_NODES, 64, 0, stream>>>(hbf, pbuf, rowptr, srcs, rden, b3, Wc, bc,
                                               (float*)d_out);
}

// Round 14
// 439.487 us; speedup vs baseline: 1.2182x; 1.1447x over previous
//
#include <hip/hip_runtime.h>
#include <hip/hip_bf16.h>
#include <math.h>

#define N_NODES 50000
#define N_EDGES 400000
#define E_TOT   (N_EDGES + N_NODES)   // self loops appended
#define HEADS   8
#define HID     64
#define HC      (HEADS * HID)         // 512
#define NBLK    ((N_NODES + 255) / 256)  // 196 scan blocks

typedef __attribute__((ext_vector_type(8))) short bf16x8;  // 8 bf16 (4 VGPRs)
typedef __attribute__((ext_vector_type(4))) float f32x4;

__device__ __forceinline__ float elu1(float x) { return x > 0.f ? x : __expf(x) - 1.f; }

// round-to-nearest-even fp32 -> bf16 (raw ushort)
__device__ __forceinline__ unsigned short f2bf(float x) {
    unsigned u = __float_as_uint(x);
    unsigned r = (u + 0x7FFFu + ((u >> 16) & 1u)) >> 16;
    return (unsigned short)r;
}
__device__ __forceinline__ float bf2f(unsigned short h) {
    return __uint_as_float(((unsigned)h) << 16);
}

// ---------------- CSR build (by dst) ----------------
__global__ void hist_kernel(const int* __restrict__ dst, int* __restrict__ deg) {
    int e = blockIdx.x * blockDim.x + threadIdx.x;
    if (e >= E_TOT) return;
    int d = (e < N_EDGES) ? dst[e] : (e - N_EDGES);
    atomicAdd(&deg[d], 1);
}

__global__ __launch_bounds__(256) void deg_partial_kernel(const int* __restrict__ deg,
                                                          int* __restrict__ psum) {
    __shared__ int sm[256];
    int t = threadIdx.x;
    int idx = blockIdx.x * 256 + t;
    int v = (idx < N_NODES) ? deg[idx] : 0;
    sm[t] = v;
    __syncthreads();
    for (int off = 128; off >= 1; off >>= 1) {
        if (t < off) sm[t] += sm[t + off];
        __syncthreads();
    }
    if (t == 0) psum[blockIdx.x] = sm[0];
}

__global__ __launch_bounds__(256) void scan_partial_kernel(int* __restrict__ psum) {
    __shared__ int sm[256];
    int t = threadIdx.x;
    int v = (t < NBLK) ? psum[t] : 0;
    sm[t] = v;
    __syncthreads();
    for (int off = 1; off < 256; off <<= 1) {
        int add = (t >= off) ? sm[t - off] : 0;
        __syncthreads();
        sm[t] += add;
        __syncthreads();
    }
    if (t < NBLK) psum[t] = sm[t] - v;  // exclusive
}

__global__ __launch_bounds__(256) void rowptr_kernel(const int* __restrict__ deg,
                                                     const int* __restrict__ psum,
                                                     int* __restrict__ rowptr,
                                                     int* __restrict__ cursor) {
    __shared__ int sm[256];
    int t = threadIdx.x;
    int idx = blockIdx.x * 256 + t;
    int v = (idx < N_NODES) ? deg[idx] : 0;
    sm[t] = v;
    __syncthreads();
    for (int off = 1; off < 256; off <<= 1) {
        int add = (t >= off) ? sm[t - off] : 0;
        __syncthreads();
        sm[t] += add;
        __syncthreads();
    }
    if (idx < N_NODES) {
        int r = psum[blockIdx.x] + sm[t] - v;  // exclusive
        rowptr[idx] = r;
        cursor[idx] = r;
    }
    if (idx == 0) rowptr[N_NODES] = E_TOT;
}

__global__ void scatter_kernel(const int* __restrict__ srcrow, const int* __restrict__ dstrow,
                               int* __restrict__ cursor, int* __restrict__ src_sorted) {
    int e = blockIdx.x * blockDim.x + threadIdx.x;
    if (e >= E_TOT) return;
    int s, d;
    if (e < N_EDGES) { s = srcrow[e]; d = dstrow[e]; }
    else             { s = d = e - N_EDGES; }
    int pos = atomicAdd(&cursor[d], 1);
    src_sorted[pos] = s;
}

// ---------------- fused layer-1 GEMM + score: [N,5]@[5,512] -> bf16 h, ssrc/sdst --------------
// One wave per node; lane holds channels c = lane*8..lane*8+7 in fp32 registers.
// Head = lane>>3 (8 lanes x 8 ch = 64 ch per head); 8-lane shfl_xor reduce -> scores.
__global__ __launch_bounds__(256) void gemm5score_kernel(
    const float* __restrict__ x, const float* __restrict__ W,
    const float* __restrict__ a_src, const float* __restrict__ a_dst,
    unsigned short* __restrict__ h, float* __restrict__ ssrc, float* __restrict__ sdst) {
    int wave = threadIdx.x >> 6, lane = threadIdx.x & 63;
    int n = blockIdx.x * 4 + wave;   // 50000 / 4 = 12500 blocks exactly
    float xr[5];
#pragma unroll
    for (int k = 0; k < 5; ++k) xr[k] = x[n * 5 + k];
    int c0 = lane * 8;
    float hv[8];
#pragma unroll
    for (int q = 0; q < 8; ++q) {
        float acc = 0.f;
#pragma unroll
        for (int k = 0; k < 5; ++k) acc = fmaf(xr[k], W[k * 512 + c0 + q], acc);
        hv[q] = acc;
    }
    unsigned short hp[8];
#pragma unroll
    for (int q = 0; q < 8; ++q) hp[q] = f2bf(hv[q]);
    *(uint4*)(h + (size_t)n * 512 + c0) = *(const uint4*)hp;  // 16B-aligned coalesced row write

    int head = lane >> 3;
    int cb = (lane & 7) * 8;
    float s1 = 0.f, s2 = 0.f;
#pragma unroll
    for (int q = 0; q < 8; ++q) {
        s1 = fmaf(hv[q], a_src[head * 64 + cb + q], s1);
        s2 = fmaf(hv[q], a_dst[head * 64 + cb + q], s2);
    }
#pragma unroll
    for (int step = 1; step <= 4; step <<= 1) {
        s1 += __shfl_xor(s1, step, 64);
        s2 += __shfl_xor(s2, step, 64);
    }
    if ((lane & 7) == 0) {
        ssrc[n * 8 + head] = s1;
        sdst[n * 8 + head] = s2;
    }
}

// ---------------- W -> W^T bf16: W[512][NCOL] -> Wt[NCOL][512] ----------------
template <int NCOL>
__global__ void wtrans_kernel(const float* __restrict__ W, unsigned short* __restrict__ hi) {
    int idx = blockIdx.x * 256 + threadIdx.x;
    if (idx >= 512 * NCOL) return;
    int k = idx / NCOL, n = idx % NCOL;
    hi[(size_t)n * 512 + k] = f2bf(W[idx]);
}

// ---------------- bf16 MFMA GEMM + fused score epilogue ----------------
// LDS rows of 64B; 16B-slot p holds k-chunk g = p ^ ((row>>1)&3) (zero-conflict, R5-measured).
// Full 128B-line staging per row via back-to-back half-chunks (R6).
template <int ROWS, int NW>
__device__ __forceinline__ void stage_pair(const unsigned short* __restrict__ src, int row0,
                                           int maxRow, int k0, char* lds0, char* lds1,
                                           int wave, int lane) {
    constexpr int CHUNKS = ROWS / 16;  // 1KB chunks (16 rows x 64B) per half
    for (int c = wave; c < CHUNKS; c += NW) {
        int r = c * 16 + (lane >> 2);
        int p = lane & 3;
        int g = p ^ ((r >> 1) & 3);
        int gr = row0 + r;
        if (gr > maxRow) gr = maxRow;  // tail clamp; result write-guarded
        const unsigned short* gp = src + (size_t)gr * 512 + k0 + g * 8;
        __builtin_amdgcn_global_load_lds((const __attribute__((address_space(1))) void*)gp,
                                         (__attribute__((address_space(3))) void*)(lds0 + c * 1024),
                                         16, 0, 0);
        __builtin_amdgcn_global_load_lds((const __attribute__((address_space(1))) void*)(gp + 32),
                                         (__attribute__((address_space(3))) void*)(lds1 + c * 1024),
                                         16, 0, 0);
    }
}

// 1D grid, y-grouped XCD swizzle (T1). SCORE epilogue (R13-proven): wave wc covers exactly
// 64 cols = one head, s_src/s_dst computed from fp32 acc in-register (m89 C/D layout).
template <int BM, int BN, int WM, int WN, int GX, int SH, bool SCORE>
__global__ __launch_bounds__(WM * WN * 64) void gemm_mfma(
    const unsigned short* __restrict__ A, const unsigned short* __restrict__ B,
    unsigned short* __restrict__ C,
    const float* __restrict__ asrc, const float* __restrict__ adst,
    float* __restrict__ ssrc, float* __restrict__ sdst,
    int M, int Nout, int maxRowB) {
    constexpr int NW = WM * WN;
    constexpr int MI = BM / (16 * WM);
    constexpr int NI = BN / (16 * WN);
    static_assert(!SCORE || NI * 16 == 64, "score epilogue needs 64 cols per wave");
    constexpr int ABYTES = BM * 64;
    constexpr int BBYTES = BN * 64;
    constexpr int GRPS = GX * 8;
    __shared__ __attribute__((aligned(16))) char lds[(ABYTES + BBYTES) * 2];
    char* const pA0 = lds;
    char* const pA1 = pA0 + ABYTES;
    char* const pB0 = pA1 + ABYTES;
    char* const pB1 = pB0 + BBYTES;

    const int wg = blockIdx.x;
    const int bx = (wg % GRPS) >> 3;
    const int by = (wg / GRPS) * 8 + (wg & 7);
    if (by * BM >= M) return;  // whole block exits before any barrier
    const int m0 = by * BM, n0 = bx * BN;

    const int t = threadIdx.x, lane = t & 63, wave = t >> 6;
    const int wr = wave / WN, wc = wave % WN;

    int offA[MI], offB[NI];
#pragma unroll
    for (int s = 0; s < MI; ++s) {
        int rA = (wr * MI + s) * 16 + (lane & 15);
        offA[s] = rA * 64 + ((((lane >> 4) ^ ((rA >> 1) & 3))) << 4);
    }
#pragma unroll
    for (int s = 0; s < NI; ++s) {
        int rB = (wc * NI + s) * 16 + (lane & 15);
        offB[s] = rB * 64 + ((((lane >> 4) ^ ((rB >> 1) & 3))) << 4);
    }

    f32x4 acc[MI][NI] = {};

    for (int k0 = 0; k0 < 512; k0 += 64) {
        stage_pair<BM, NW>(A, m0, M - 1,   k0, pA0, pA1, wave, lane);
        stage_pair<BN, NW>(B, n0, maxRowB, k0, pB0, pB1, wave, lane);
        __syncthreads();  // compiler drains vmcnt before barrier -> LDS valid

#pragma unroll
        for (int half = 0; half < 2; ++half) {
            const char* cA = half ? pA1 : pA0;
            const char* cB = half ? pB1 : pB0;
            bf16x8 av[MI], bv[NI];
#pragma unroll
            for (int s = 0; s < MI; ++s) av[s] = *(const bf16x8*)(cA + offA[s]);
#pragma unroll
            for (int s = 0; s < NI; ++s) bv[s] = *(const bf16x8*)(cB + offB[s]);
#pragma unroll
            for (int i = 0; i < MI; ++i)
#pragma unroll
                for (int j = 0; j < NI; ++j)
                    acc[i][j] = __builtin_amdgcn_mfma_f32_16x16x32_bf16(av[i], bv[j], acc[i][j], 0, 0, 0);
        }
        __syncthreads();
    }

    // C/D layout (m89-verified): col = lane&15, row = (lane>>4)*4 + reg
#pragma unroll
    for (int i = 0; i < MI; ++i) {
        int row = m0 + (wr * MI + i) * 16 + ((lane >> 4) << 2);
#pragma unroll
        for (int j = 0; j < NI; ++j) {
            int col = n0 + (wc * NI + j) * 16 + (lane & 15);
            f32x4 v = acc[i][j];
#pragma unroll
            for (int r = 0; r < 4; ++r) {
                if (row + r < M) C[(size_t)(row + r) * Nout + col] = f2bf(v[r]);
            }
        }
    }

    if constexpr (SCORE) {
        const int head = n0 / 64 + wc;   // wave's 64 columns == this head
        float aS[NI], aD[NI];
#pragma unroll
        for (int j = 0; j < NI; ++j) {
            int cl = j * 16 + (lane & 15);
            aS[j] = asrc[head * 64 + cl];
            aD[j] = adst[head * 64 + cl];
        }
        float Ps[MI][4], Pd[MI][4];
#pragma unroll
        for (int i = 0; i < MI; ++i)
#pragma unroll
            for (int r = 0; r < 4; ++r) { Ps[i][r] = 0.f; Pd[i][r] = 0.f; }
#pragma unroll
        for (int i = 0; i < MI; ++i)
#pragma unroll
            for (int j = 0; j < NI; ++j)
#pragma unroll
                for (int r = 0; r < 4; ++r) {
                    Ps[i][r] = fmaf(acc[i][j][r], aS[j], Ps[i][r]);
                    Pd[i][r] = fmaf(acc[i][j][r], aD[j], Pd[i][r]);
                }
#pragma unroll
        for (int step = 1; step <= 8; step <<= 1) {
#pragma unroll
            for (int i = 0; i < MI; ++i)
#pragma unroll
                for (int r = 0; r < 4; ++r) {
                    Ps[i][r] += __shfl_xor(Ps[i][r], step, 64);
                    Pd[i][r] += __shfl_xor(Pd[i][r], step, 64);
                }
        }
        int idx = lane & 15, g = lane >> 4;
        if (idx < MI * 4) {
            float vs = 0.f, vd = 0.f;
#pragma unroll
            for (int i = 0; i < MI; ++i)
#pragma unroll
                for (int r = 0; r < 4; ++r) {
                    bool sel = (idx == i * 4 + r);
                    vs = sel ? Ps[i][r] : vs;
                    vd = sel ? Pd[i][r] : vd;
                }
            int ii = idx >> 2, rr = idx & 3;
            int row = m0 + (wr * MI + ii) * 16 + g * 4 + rr;
            if (row < M) {
                ssrc[(size_t)row * SH + head] = vs;
                sdst[(size_t)row * SH + head] = vd;
            }
        }
    }
}

// ---------------- per-(dst,head) softmax: SINGLE-PASS (no max; softmax shift-invariance) -------
// R14: alpha = exp(e)/sum(exp(e)) exactly equals the max-subtracted form; scores bounded ~|30|
// << fp32 exp range. One gather pass + one pbuf write (was 3 passes).
template <int H>
__global__ void softmax_kernel(const int* __restrict__ rowptr, const int* __restrict__ srcs,
                               const float* __restrict__ ssrc, const float* __restrict__ sdst,
                               float* __restrict__ p, float* __restrict__ rden) {
    int gid = blockIdx.x * blockDim.x + threadIdx.x;
    if (gid >= N_NODES * H) return;
    int n = gid / H, hh = gid % H;
    int lo = rowptr[n], hi = rowptr[n + 1];
    float sd = sdst[gid];
    float su0 = 0.f, su1 = 0.f, su2 = 0.f, su3 = 0.f;
    int j = lo;
    for (; j + 4 <= hi; j += 4) {
        int s0 = srcs[j], s1 = srcs[j + 1], s2 = srcs[j + 2], s3 = srcs[j + 3];
        float v0 = ssrc[s0 * H + hh] + sd;
        float v1 = ssrc[s1 * H + hh] + sd;
        float v2 = ssrc[s2 * H + hh] + sd;
        float v3 = ssrc[s3 * H + hh] + sd;
        v0 = v0 > 0.f ? v0 : 0.2f * v0;
        v1 = v1 > 0.f ? v1 : 0.2f * v1;
        v2 = v2 > 0.f ? v2 : 0.2f * v2;
        v3 = v3 > 0.f ? v3 : 0.2f * v3;
        float e0 = __expf(v0), e1 = __expf(v1), e2 = __expf(v2), e3 = __expf(v3);
        p[(size_t)j * H + hh] = e0;
        p[(size_t)(j + 1) * H + hh] = e1;
        p[(size_t)(j + 2) * H + hh] = e2;
        p[(size_t)(j + 3) * H + hh] = e3;
        su0 += e0; su1 += e1; su2 += e2; su3 += e3;
    }
    for (; j < hi; ++j) {
        float v = ssrc[srcs[j] * H + hh] + sd;
        v = v > 0.f ? v : 0.2f * v;
        float e = __expf(v);
        p[(size_t)j * H + hh] = e;
        su0 += e;
    }
    float sum = (su0 + su1) + (su2 + su3);
    rden[gid] = 1.f / (sum + 1e-16f);
}

// ---------------- gather-aggregate (8 heads, 512 ch) + bias + ELU -> bf16 out (R7-proven) ------
__global__ __launch_bounds__(256) void agg8_kernel(const unsigned short* __restrict__ h,
                                                   const float* __restrict__ p,
                                                   const int* __restrict__ rowptr,
                                                   const int* __restrict__ srcs,
                                                   const float* __restrict__ rden,
                                                   const float* __restrict__ bias,
                                                   unsigned short* __restrict__ out) {
    int n = blockIdx.x;
    int t = threadIdx.x;           // pair index: channels 2t, 2t+1 (same head)
    int hh = t >> 5;               // (2t)/64
    int lo = rowptr[n], hi = rowptr[n + 1];
    float rd = rden[n * 8 + hh];
    float a0 = 0.f, a1 = 0.f, b0 = 0.f, b1 = 0.f;
    float c0 = 0.f, c1 = 0.f, d0 = 0.f, d1 = 0.f;
    int j = lo;
    for (; j + 4 <= hi; j += 4) {
        int s0 = srcs[j], s1 = srcs[j + 1], s2 = srcs[j + 2], s3 = srcs[j + 3];
        unsigned v0 = *(const unsigned*)(h + (size_t)s0 * 512 + 2 * t);
        unsigned v1 = *(const unsigned*)(h + (size_t)s1 * 512 + 2 * t);
        unsigned v2 = *(const unsigned*)(h + (size_t)s2 * 512 + 2 * t);
        unsigned v3 = *(const unsigned*)(h + (size_t)s3 * 512 + 2 * t);
        float p0 = p[(size_t)j * 8 + hh];
        float p1 = p[(size_t)(j + 1) * 8 + hh];
        float p2 = p[(size_t)(j + 2) * 8 + hh];
        float p3 = p[(size_t)(j + 3) * 8 + hh];
        a0 = fmaf(p0, bf2f((unsigned short)(v0 & 0xffff)), a0);
        a1 = fmaf(p0, bf2f((unsigned short)(v0 >> 16)), a1);
        b0 = fmaf(p1, bf2f((unsigned short)(v1 & 0xffff)), b0);
        b1 = fmaf(p1, bf2f((unsigned short)(v1 >> 16)), b1);
        c0 = fmaf(p2, bf2f((unsigned short)(v2 & 0xffff)), c0);
        c1 = fmaf(p2, bf2f((unsigned short)(v2 >> 16)), c1);
        d0 = fmaf(p3, bf2f((unsigned short)(v3 & 0xffff)), d0);
        d1 = fmaf(p3, bf2f((unsigned short)(v3 >> 16)), d1);
    }
    for (; j < hi; ++j) {
        int s = srcs[j];
        unsigned v = *(const unsigned*)(h + (size_t)s * 512 + 2 * t);
        float pj = p[(size_t)j * 8 + hh];
        a0 = fmaf(pj, bf2f((unsigned short)(v & 0xffff)), a0);
        a1 = fmaf(pj, bf2f((unsigned short)(v >> 16)), a1);
    }
    float s0 = (a0 + b0) + (c0 + d0);
    float s1 = (a1 + b1) + (c1 + d1);
    float2 bv = *(const float2*)(bias + 2 * t);
    float v0 = elu1(s0 * rd + bv.x);
    float v1 = elu1(s1 * rd + bv.y);
    unsigned pack = (unsigned)f2bf(v0) | ((unsigned)f2bf(v1) << 16);
    *(unsigned*)(out + (size_t)n * 512 + 2 * t) = pack;
}

// ---------------- fused gather-aggregate (1 head) + bias + ELU + classifier -> sigmoid ---------
__global__ __launch_bounds__(64) void agg1cls_kernel(const unsigned short* __restrict__ h,
                                                     const float* __restrict__ p,
                                                     const int* __restrict__ rowptr,
                                                     const int* __restrict__ srcs,
                                                     const float* __restrict__ rden,
                                                     const float* __restrict__ bias,
                                                     const float* __restrict__ Wc,
                                                     const float* __restrict__ bc,
                                                     float* __restrict__ out) {
    int n = blockIdx.x;
    int t = threadIdx.x;
    int lo = rowptr[n], hi = rowptr[n + 1];
    float rd = rden[n];
    float a = 0.f, b = 0.f, c = 0.f, d = 0.f;
    int j = lo;
    for (; j + 4 <= hi; j += 4) {
        int s0 = srcs[j], s1 = srcs[j + 1], s2 = srcs[j + 2], s3 = srcs[j + 3];
        float h0 = bf2f(h[(size_t)s0 * 64 + t]);
        float h1 = bf2f(h[(size_t)s1 * 64 + t]);
        float h2 = bf2f(h[(size_t)s2 * 64 + t]);
        float h3 = bf2f(h[(size_t)s3 * 64 + t]);
        a = fmaf(p[j], h0, a);
        b = fmaf(p[j + 1], h1, b);
        c = fmaf(p[j + 2], h2, c);
        d = fmaf(p[j + 3], h3, d);
    }
    for (; j < hi; ++j) {
        a = fmaf(p[j], bf2f(h[(size_t)srcs[j] * 64 + t]), a);
    }
    float acc = (a + b) + (c + d);
    float v = elu1(acc * rd + bias[t]);
    float prod = v * Wc[t];
#pragma unroll
    for (int off = 32; off >= 1; off >>= 1) prod += __shfl_down(prod, off);
    if (t == 0) out[n] = 1.f / (1.f + __expf(-(prod + bc[0])));
}

extern "C" void kernel_launch(void* const* d_in, const int* in_sizes, int n_in,
                              void* d_out, int out_size, void* d_ws, size_t ws_size,
                              hipStream_t stream) {
    const float* x   = (const float*)d_in[0];
    const int*   ei  = (const int*)d_in[1];
    const int* src_row = ei;
    const int* dst_row = ei + N_EDGES;
    const float* W1  = (const float*)d_in[2];
    const float* as1 = (const float*)d_in[3];
    const float* ad1 = (const float*)d_in[4];
    const float* b1  = (const float*)d_in[5];
    const float* W2  = (const float*)d_in[6];
    const float* as2 = (const float*)d_in[7];
    const float* ad2 = (const float*)d_in[8];
    const float* b2  = (const float*)d_in[9];
    const float* W3  = (const float*)d_in[10];
    const float* as3 = (const float*)d_in[11];
    const float* ad3 = (const float*)d_in[12];
    const float* b3  = (const float*)d_in[13];
    const float* Wc  = (const float*)d_in[14];
    const float* bc  = (const float*)d_in[15];

    char* w = (char*)d_ws;
    auto alloc = [&](size_t bytes) -> void* {
        void* ptr = (void*)w;
        w += (bytes + 255) & ~(size_t)255;
        return ptr;
    };
    int*   deg    = (int*)alloc((size_t)N_NODES * 4);
    int*   rowptr = (int*)alloc((size_t)(N_NODES + 1) * 4);
    int*   cursor = (int*)alloc((size_t)N_NODES * 4);
    int*   srcs   = (int*)alloc((size_t)E_TOT * 4);
    int*   psum   = (int*)alloc((size_t)NBLK * 4);
    float* pbuf   = (float*)alloc((size_t)E_TOT * HEADS * 4);
    float* ssrc   = (float*)alloc((size_t)N_NODES * HEADS * 4);
    float* sdst   = (float*)alloc((size_t)N_NODES * HEADS * 4);
    float* rden   = (float*)alloc((size_t)N_NODES * HEADS * 4);
    unsigned short* hbf = (unsigned short*)alloc((size_t)N_NODES * HC * 2);  // bf16 h (GEMM out)
    unsigned short* gbf = (unsigned short*)alloc((size_t)N_NODES * HC * 2);  // agg out (bf16)
    unsigned short* w2t = (unsigned short*)alloc((size_t)512 * 512 * 2);
    unsigned short* w3t = (unsigned short*)alloc((size_t)64 * 512 * 2);

    hipMemsetAsync(deg, 0, (size_t)N_NODES * 4, stream);

    const int EB = (E_TOT + 255) / 256;
    hist_kernel<<<EB, 256, 0, stream>>>(dst_row, deg);
    deg_partial_kernel<<<NBLK, 256, 0, stream>>>(deg, psum);
    scan_partial_kernel<<<1, 256, 0, stream>>>(psum);
    rowptr_kernel<<<NBLK, 256, 0, stream>>>(deg, psum, rowptr, cursor);
    scatter_kernel<<<EB, 256, 0, stream>>>(src_row, dst_row, cursor, srcs);

    // weight transpose (bf16, tiny; once per call)
    wtrans_kernel<512><<<(512 * 512 + 255) / 256, 256, 0, stream>>>(W2, w2t);
    wtrans_kernel<64><<<(512 * 64 + 255) / 256, 256, 0, stream>>>(W3, w3t);

    const int NHB = (N_NODES * HEADS + 255) / 256;
    const int NB  = (N_NODES + 255) / 256;
    const int MB128 = (N_NODES + 127) / 128;                 // 391
    const int G2 = ((MB128 + 7) / 8) * 32;                   // 49 groups x (4x * 8y) = 1568
    const int MB64 = (N_NODES + 63) / 64;                    // 782
    const int G3 = ((MB64 + 7) / 8) * 8;                     // 784

    // ---- layer 1: fused x@W1 + score -> hbf, ssrc/sdst -> softmax -> agg -> gbf ----
    gemm5score_kernel<<<N_NODES / 4, 256, 0, stream>>>(x, W1, as1, ad1, hbf, ssrc, sdst);
    softmax_kernel<8><<<NHB, 256, 0, stream>>>(rowptr, srcs, ssrc, sdst, pbuf, rden);
    agg8_kernel<<<N_NODES, 256, 0, stream>>>(hbf, pbuf, rowptr, srcs, rden, b1, gbf);

    // ---- layer 2: gbf @ W2 (bf16 MFMA + fused score) -> hbf, ssrc/sdst -> softmax -> agg ----
    gemm_mfma<128, 128, 2, 2, 4, 8, true><<<G2, 256, 0, stream>>>(
        gbf, w2t, hbf, as2, ad2, ssrc, sdst, N_NODES, 512, 511);
    softmax_kernel<8><<<NHB, 256, 0, stream>>>(rowptr, srcs, ssrc, sdst, pbuf, rden);
    agg8_kernel<<<N_NODES, 256, 0, stream>>>(hbf, pbuf, rowptr, srcs, rden, b2, gbf);

    // ---- layer 3: gbf @ W3 (BM=64, fused score, 1 head) -> softmax -> fused agg+cls ----
    gemm_mfma<64, 64, 2, 1, 1, 1, true><<<G3, 128, 0, stream>>>(
        gbf, w3t, hbf, as3, ad3, ssrc, sdst, N_NODES, 64, 63);
    softmax_kernel<1><<<NB, 256, 0, stream>>>(rowptr, srcs, ssrc, sdst, pbuf, rden);
    agg1cls_kernel<<<N_NODES, 64, 0, stream>>>(hbf, pbuf, rowptr, srcs, rden, b3, Wc, bc,
                                               (float*)d_out);
}

// Round 15
// 424.411 us; speedup vs baseline: 1.2614x; 1.0355x over previous
//
#include <hip/hip_runtime.h>
#include <hip/hip_bf16.h>
#include <math.h>

#define N_NODES 50000
#define N_EDGES 400000
#define E_TOT   (N_EDGES + N_NODES)   // self loops appended
#define HEADS   8
#define HID     64
#define HC      (HEADS * HID)         // 512
#define NBLK    ((N_NODES + 255) / 256)  // 196 scan blocks

typedef __attribute__((ext_vector_type(8))) short bf16x8;  // 8 bf16 (4 VGPRs)
typedef __attribute__((ext_vector_type(4))) float f32x4;

__device__ __forceinline__ float elu1(float x) { return x > 0.f ? x : __expf(x) - 1.f; }

// round-to-nearest-even fp32 -> bf16 (raw ushort)
__device__ __forceinline__ unsigned short f2bf(float x) {
    unsigned u = __float_as_uint(x);
    unsigned r = (u + 0x7FFFu + ((u >> 16) & 1u)) >> 16;
    return (unsigned short)r;
}
__device__ __forceinline__ float bf2f(unsigned short h) {
    return __uint_as_float(((unsigned)h) << 16);
}

// ---------------- CSR build (by dst) ----------------
__global__ void hist_kernel(const int* __restrict__ dst, int* __restrict__ deg) {
    int e = blockIdx.x * blockDim.x + threadIdx.x;
    if (e >= E_TOT) return;
    int d = (e < N_EDGES) ? dst[e] : (e - N_EDGES);
    atomicAdd(&deg[d], 1);
}

__global__ __launch_bounds__(256) void deg_partial_kernel(const int* __restrict__ deg,
                                                          int* __restrict__ psum) {
    __shared__ int sm[256];
    int t = threadIdx.x;
    int idx = blockIdx.x * 256 + t;
    int v = (idx < N_NODES) ? deg[idx] : 0;
    sm[t] = v;
    __syncthreads();
    for (int off = 128; off >= 1; off >>= 1) {
        if (t < off) sm[t] += sm[t + off];
        __syncthreads();
    }
    if (t == 0) psum[blockIdx.x] = sm[0];
}

__global__ __launch_bounds__(256) void scan_partial_kernel(int* __restrict__ psum) {
    __shared__ int sm[256];
    int t = threadIdx.x;
    int v = (t < NBLK) ? psum[t] : 0;
    sm[t] = v;
    __syncthreads();
    for (int off = 1; off < 256; off <<= 1) {
        int add = (t >= off) ? sm[t - off] : 0;
        __syncthreads();
        sm[t] += add;
        __syncthreads();
    }
    if (t < NBLK) psum[t] = sm[t] - v;  // exclusive
}

__global__ __launch_bounds__(256) void rowptr_kernel(const int* __restrict__ deg,
                                                     const int* __restrict__ psum,
                                                     int* __restrict__ rowptr,
                                                     int* __restrict__ cursor) {
    __shared__ int sm[256];
    int t = threadIdx.x;
    int idx = blockIdx.x * 256 + t;
    int v = (idx < N_NODES) ? deg[idx] : 0;
    sm[t] = v;
    __syncthreads();
    for (int off = 1; off < 256; off <<= 1) {
        int add = (t >= off) ? sm[t - off] : 0;
        __syncthreads();
        sm[t] += add;
        __syncthreads();
    }
    if (idx < N_NODES) {
        int r = psum[blockIdx.x] + sm[t] - v;  // exclusive
        rowptr[idx] = r;
        cursor[idx] = r;
    }
    if (idx == 0) rowptr[N_NODES] = E_TOT;
}

__global__ void scatter_kernel(const int* __restrict__ srcrow, const int* __restrict__ dstrow,
                               int* __restrict__ cursor, int* __restrict__ src_sorted) {
    int e = blockIdx.x * blockDim.x + threadIdx.x;
    if (e >= E_TOT) return;
    int s, d;
    if (e < N_EDGES) { s = srcrow[e]; d = dstrow[e]; }
    else             { s = d = e - N_EDGES; }
    int pos = atomicAdd(&cursor[d], 1);
    src_sorted[pos] = s;
}

// ---------------- fused layer-1 GEMM + score: [N,5]@[5,512] -> bf16 h, ssrc/sdst --------------
// One wave per node; lane holds channels c = lane*8..lane*8+7 in fp32 registers.
// Head = lane>>3 (8 lanes x 8 ch = 64 ch per head); 8-lane shfl_xor reduce -> scores.
__global__ __launch_bounds__(256) void gemm5score_kernel(
    const float* __restrict__ x, const float* __restrict__ W,
    const float* __restrict__ a_src, const float* __restrict__ a_dst,
    unsigned short* __restrict__ h, float* __restrict__ ssrc, float* __restrict__ sdst) {
    int wave = threadIdx.x >> 6, lane = threadIdx.x & 63;
    int n = blockIdx.x * 4 + wave;   // 50000 / 4 = 12500 blocks exactly
    float xr[5];
#pragma unroll
    for (int k = 0; k < 5; ++k) xr[k] = x[n * 5 + k];
    int c0 = lane * 8;
    float hv[8];
#pragma unroll
    for (int q = 0; q < 8; ++q) {
        float acc = 0.f;
#pragma unroll
        for (int k = 0; k < 5; ++k) acc = fmaf(xr[k], W[k * 512 + c0 + q], acc);
        hv[q] = acc;
    }
    unsigned short hp[8];
#pragma unroll
    for (int q = 0; q < 8; ++q) hp[q] = f2bf(hv[q]);
    *(uint4*)(h + (size_t)n * 512 + c0) = *(const uint4*)hp;  // 16B-aligned coalesced row write

    int head = lane >> 3;
    int cb = (lane & 7) * 8;
    float s1 = 0.f, s2 = 0.f;
#pragma unroll
    for (int q = 0; q < 8; ++q) {
        s1 = fmaf(hv[q], a_src[head * 64 + cb + q], s1);
        s2 = fmaf(hv[q], a_dst[head * 64 + cb + q], s2);
    }
#pragma unroll
    for (int step = 1; step <= 4; step <<= 1) {
        s1 += __shfl_xor(s1, step, 64);
        s2 += __shfl_xor(s2, step, 64);
    }
    if ((lane & 7) == 0) {
        ssrc[n * 8 + head] = s1;
        sdst[n * 8 + head] = s2;
    }
}

// ---------------- W -> W^T bf16: W[512][NCOL] -> Wt[NCOL][512] ----------------
template <int NCOL>
__global__ void wtrans_kernel(const float* __restrict__ W, unsigned short* __restrict__ hi) {
    int idx = blockIdx.x * 256 + threadIdx.x;
    if (idx >= 512 * NCOL) return;
    int k = idx / NCOL, n = idx % NCOL;
    hi[(size_t)n * 512 + k] = f2bf(W[idx]);
}

// ---------------- bf16 MFMA GEMM + fused score epilogue ----------------
// LDS rows of 64B; 16B-slot p holds k-chunk g = p ^ ((row>>1)&3) (zero-conflict, R5-measured).
// Full 128B-line staging per row via back-to-back half-chunks (R6).
template <int ROWS, int NW>
__device__ __forceinline__ void stage_pair(const unsigned short* __restrict__ src, int row0,
                                           int maxRow, int k0, char* lds0, char* lds1,
                                           int wave, int lane) {
    constexpr int CHUNKS = ROWS / 16;  // 1KB chunks (16 rows x 64B) per half
    for (int c = wave; c < CHUNKS; c += NW) {
        int r = c * 16 + (lane >> 2);
        int p = lane & 3;
        int g = p ^ ((r >> 1) & 3);
        int gr = row0 + r;
        if (gr > maxRow) gr = maxRow;  // tail clamp; result write-guarded
        const unsigned short* gp = src + (size_t)gr * 512 + k0 + g * 8;
        __builtin_amdgcn_global_load_lds((const __attribute__((address_space(1))) void*)gp,
                                         (__attribute__((address_space(3))) void*)(lds0 + c * 1024),
                                         16, 0, 0);
        __builtin_amdgcn_global_load_lds((const __attribute__((address_space(1))) void*)(gp + 32),
                                         (__attribute__((address_space(3))) void*)(lds1 + c * 1024),
                                         16, 0, 0);
    }
}

// 1D grid, y-grouped XCD swizzle (T1). SCORE epilogue (R13-proven): wave wc covers exactly
// 64 cols = one head, s_src/s_dst computed from fp32 acc in-register (m89 C/D layout).
template <int BM, int BN, int WM, int WN, int GX, int SH, bool SCORE>
__global__ __launch_bounds__(WM * WN * 64) void gemm_mfma(
    const unsigned short* __restrict__ A, const unsigned short* __restrict__ B,
    unsigned short* __restrict__ C,
    const float* __restrict__ asrc, const float* __restrict__ adst,
    float* __restrict__ ssrc, float* __restrict__ sdst,
    int M, int Nout, int maxRowB) {
    constexpr int NW = WM * WN;
    constexpr int MI = BM / (16 * WM);
    constexpr int NI = BN / (16 * WN);
    static_assert(!SCORE || NI * 16 == 64, "score epilogue needs 64 cols per wave");
    constexpr int ABYTES = BM * 64;
    constexpr int BBYTES = BN * 64;
    constexpr int GRPS = GX * 8;
    __shared__ __attribute__((aligned(16))) char lds[(ABYTES + BBYTES) * 2];
    char* const pA0 = lds;
    char* const pA1 = pA0 + ABYTES;
    char* const pB0 = pA1 + ABYTES;
    char* const pB1 = pB0 + BBYTES;

    const int wg = blockIdx.x;
    const int bx = (wg % GRPS) >> 3;
    const int by = (wg / GRPS) * 8 + (wg & 7);
    if (by * BM >= M) return;  // whole block exits before any barrier
    const int m0 = by * BM, n0 = bx * BN;

    const int t = threadIdx.x, lane = t & 63, wave = t >> 6;
    const int wr = wave / WN, wc = wave % WN;

    int offA[MI], offB[NI];
#pragma unroll
    for (int s = 0; s < MI; ++s) {
        int rA = (wr * MI + s) * 16 + (lane & 15);
        offA[s] = rA * 64 + ((((lane >> 4) ^ ((rA >> 1) & 3))) << 4);
    }
#pragma unroll
    for (int s = 0; s < NI; ++s) {
        int rB = (wc * NI + s) * 16 + (lane & 15);
        offB[s] = rB * 64 + ((((lane >> 4) ^ ((rB >> 1) & 3))) << 4);
    }

    f32x4 acc[MI][NI] = {};

    for (int k0 = 0; k0 < 512; k0 += 64) {
        stage_pair<BM, NW>(A, m0, M - 1,   k0, pA0, pA1, wave, lane);
        stage_pair<BN, NW>(B, n0, maxRowB, k0, pB0, pB1, wave, lane);
        __syncthreads();  // compiler drains vmcnt before barrier -> LDS valid

#pragma unroll
        for (int half = 0; half < 2; ++half) {
            const char* cA = half ? pA1 : pA0;
            const char* cB = half ? pB1 : pB0;
            bf16x8 av[MI], bv[NI];
#pragma unroll
            for (int s = 0; s < MI; ++s) av[s] = *(const bf16x8*)(cA + offA[s]);
#pragma unroll
            for (int s = 0; s < NI; ++s) bv[s] = *(const bf16x8*)(cB + offB[s]);
#pragma unroll
            for (int i = 0; i < MI; ++i)
#pragma unroll
                for (int j = 0; j < NI; ++j)
                    acc[i][j] = __builtin_amdgcn_mfma_f32_16x16x32_bf16(av[i], bv[j], acc[i][j], 0, 0, 0);
        }
        __syncthreads();
    }

    // C/D layout (m89-verified): col = lane&15, row = (lane>>4)*4 + reg
#pragma unroll
    for (int i = 0; i < MI; ++i) {
        int row = m0 + (wr * MI + i) * 16 + ((lane >> 4) << 2);
#pragma unroll
        for (int j = 0; j < NI; ++j) {
            int col = n0 + (wc * NI + j) * 16 + (lane & 15);
            f32x4 v = acc[i][j];
#pragma unroll
            for (int r = 0; r < 4; ++r) {
                if (row + r < M) C[(size_t)(row + r) * Nout + col] = f2bf(v[r]);
            }
        }
    }

    if constexpr (SCORE) {
        const int head = n0 / 64 + wc;   // wave's 64 columns == this head
        float aS[NI], aD[NI];
#pragma unroll
        for (int j = 0; j < NI; ++j) {
            int cl = j * 16 + (lane & 15);
            aS[j] = asrc[head * 64 + cl];
            aD[j] = adst[head * 64 + cl];
        }
        float Ps[MI][4], Pd[MI][4];
#pragma unroll
        for (int i = 0; i < MI; ++i)
#pragma unroll
            for (int r = 0; r < 4; ++r) { Ps[i][r] = 0.f; Pd[i][r] = 0.f; }
#pragma unroll
        for (int i = 0; i < MI; ++i)
#pragma unroll
            for (int j = 0; j < NI; ++j)
#pragma unroll
                for (int r = 0; r < 4; ++r) {
                    Ps[i][r] = fmaf(acc[i][j][r], aS[j], Ps[i][r]);
                    Pd[i][r] = fmaf(acc[i][j][r], aD[j], Pd[i][r]);
                }
#pragma unroll
        for (int step = 1; step <= 8; step <<= 1) {
#pragma unroll
            for (int i = 0; i < MI; ++i)
#pragma unroll
                for (int r = 0; r < 4; ++r) {
                    Ps[i][r] += __shfl_xor(Ps[i][r], step, 64);
                    Pd[i][r] += __shfl_xor(Pd[i][r], step, 64);
                }
        }
        int idx = lane & 15, g = lane >> 4;
        if (idx < MI * 4) {
            float vs = 0.f, vd = 0.f;
#pragma unroll
            for (int i = 0; i < MI; ++i)
#pragma unroll
                for (int r = 0; r < 4; ++r) {
                    bool sel = (idx == i * 4 + r);
                    vs = sel ? Ps[i][r] : vs;
                    vd = sel ? Pd[i][r] : vd;
                }
            int ii = idx >> 2, rr = idx & 3;
            int row = m0 + (wr * MI + ii) * 16 + g * 4 + rr;
            if (row < M) {
                ssrc[(size_t)row * SH + head] = vs;
                sdst[(size_t)row * SH + head] = vd;
            }
        }
    }
}

// ---------------- fully-fused softmax + gather-aggregate (8 heads, 512 ch) -> bf16 out ---------
// R15: p_j = exp(lrelu(ssrc[s_j]+sdst[n])) computed inline (no-max softmax is single-pass, R14);
// denominator accumulated alongside. Deletes softmax kernels + the entire pbuf round-trip.
// No barriers / LDS — the R7-proven 4-wide gather pipeline is untouched; ssrc is 1.6MB
// L2-resident so the extra 4B gather is cheap; exp runs on the idle trans pipe.
__global__ __launch_bounds__(256) void agg8sf_kernel(const unsigned short* __restrict__ h,
                                                     const float* __restrict__ ssrc,
                                                     const float* __restrict__ sdst,
                                                     const int* __restrict__ rowptr,
                                                     const int* __restrict__ srcs,
                                                     const float* __restrict__ bias,
                                                     unsigned short* __restrict__ out) {
    int n = blockIdx.x;
    int t = threadIdx.x;           // pair index: channels 2t, 2t+1 (same head)
    int hh = t >> 5;               // (2t)/64
    int lo = rowptr[n], hi = rowptr[n + 1];
    float sd = sdst[n * 8 + hh];
    float a0 = 0.f, a1 = 0.f, b0 = 0.f, b1 = 0.f;
    float c0 = 0.f, c1 = 0.f, d0 = 0.f, d1 = 0.f;
    float q0 = 0.f, q1 = 0.f, q2 = 0.f, q3 = 0.f;   // p-sums
    int j = lo;
    for (; j + 4 <= hi; j += 4) {
        int s0 = srcs[j], s1 = srcs[j + 1], s2 = srcs[j + 2], s3 = srcs[j + 3];
        unsigned v0 = *(const unsigned*)(h + (size_t)s0 * 512 + 2 * t);
        unsigned v1 = *(const unsigned*)(h + (size_t)s1 * 512 + 2 * t);
        unsigned v2 = *(const unsigned*)(h + (size_t)s2 * 512 + 2 * t);
        unsigned v3 = *(const unsigned*)(h + (size_t)s3 * 512 + 2 * t);
        float e0 = ssrc[s0 * 8 + hh] + sd;
        float e1 = ssrc[s1 * 8 + hh] + sd;
        float e2 = ssrc[s2 * 8 + hh] + sd;
        float e3 = ssrc[s3 * 8 + hh] + sd;
        e0 = e0 > 0.f ? e0 : 0.2f * e0;
        e1 = e1 > 0.f ? e1 : 0.2f * e1;
        e2 = e2 > 0.f ? e2 : 0.2f * e2;
        e3 = e3 > 0.f ? e3 : 0.2f * e3;
        float p0 = __expf(e0), p1 = __expf(e1), p2 = __expf(e2), p3 = __expf(e3);
        q0 += p0; q1 += p1; q2 += p2; q3 += p3;
        a0 = fmaf(p0, bf2f((unsigned short)(v0 & 0xffff)), a0);
        a1 = fmaf(p0, bf2f((unsigned short)(v0 >> 16)), a1);
        b0 = fmaf(p1, bf2f((unsigned short)(v1 & 0xffff)), b0);
        b1 = fmaf(p1, bf2f((unsigned short)(v1 >> 16)), b1);
        c0 = fmaf(p2, bf2f((unsigned short)(v2 & 0xffff)), c0);
        c1 = fmaf(p2, bf2f((unsigned short)(v2 >> 16)), c1);
        d0 = fmaf(p3, bf2f((unsigned short)(v3 & 0xffff)), d0);
        d1 = fmaf(p3, bf2f((unsigned short)(v3 >> 16)), d1);
    }
    for (; j < hi; ++j) {
        int s = srcs[j];
        unsigned v = *(const unsigned*)(h + (size_t)s * 512 + 2 * t);
        float e = ssrc[s * 8 + hh] + sd;
        e = e > 0.f ? e : 0.2f * e;
        float p = __expf(e);
        q0 += p;
        a0 = fmaf(p, bf2f((unsigned short)(v & 0xffff)), a0);
        a1 = fmaf(p, bf2f((unsigned short)(v >> 16)), a1);
    }
    float sum = (q0 + q1) + (q2 + q3);
    float rd = 1.f / (sum + 1e-16f);
    float s0 = (a0 + b0) + (c0 + d0);
    float s1 = (a1 + b1) + (c1 + d1);
    float2 bv = *(const float2*)(bias + 2 * t);
    float v0 = elu1(s0 * rd + bv.x);
    float v1 = elu1(s1 * rd + bv.y);
    unsigned pack = (unsigned)f2bf(v0) | ((unsigned)f2bf(v1) << 16);
    *(unsigned*)(out + (size_t)n * 512 + 2 * t) = pack;
}

// ---------------- fully-fused softmax + agg (1 head) + bias + ELU + classifier -> sigmoid ------
__global__ __launch_bounds__(64) void agg1cls_kernel(const unsigned short* __restrict__ h,
                                                     const float* __restrict__ ssrc,
                                                     const float* __restrict__ sdst,
                                                     const int* __restrict__ rowptr,
                                                     const int* __restrict__ srcs,
                                                     const float* __restrict__ bias,
                                                     const float* __restrict__ Wc,
                                                     const float* __restrict__ bc,
                                                     float* __restrict__ out) {
    int n = blockIdx.x;
    int t = threadIdx.x;
    int lo = rowptr[n], hi = rowptr[n + 1];
    float sd = sdst[n];
    float a = 0.f, b = 0.f, c = 0.f, d = 0.f;
    float q0 = 0.f, q1 = 0.f, q2 = 0.f, q3 = 0.f;
    int j = lo;
    for (; j + 4 <= hi; j += 4) {
        int s0 = srcs[j], s1 = srcs[j + 1], s2 = srcs[j + 2], s3 = srcs[j + 3];
        float h0 = bf2f(h[(size_t)s0 * 64 + t]);
        float h1 = bf2f(h[(size_t)s1 * 64 + t]);
        float h2 = bf2f(h[(size_t)s2 * 64 + t]);
        float h3 = bf2f(h[(size_t)s3 * 64 + t]);
        float e0 = ssrc[s0] + sd, e1 = ssrc[s1] + sd, e2 = ssrc[s2] + sd, e3 = ssrc[s3] + sd;
        e0 = e0 > 0.f ? e0 : 0.2f * e0;
        e1 = e1 > 0.f ? e1 : 0.2f * e1;
        e2 = e2 > 0.f ? e2 : 0.2f * e2;
        e3 = e3 > 0.f ? e3 : 0.2f * e3;
        float p0 = __expf(e0), p1 = __expf(e1), p2 = __expf(e2), p3 = __expf(e3);
        q0 += p0; q1 += p1; q2 += p2; q3 += p3;
        a = fmaf(p0, h0, a);
        b = fmaf(p1, h1, b);
        c = fmaf(p2, h2, c);
        d = fmaf(p3, h3, d);
    }
    for (; j < hi; ++j) {
        int s = srcs[j];
        float e = ssrc[s] + sd;
        e = e > 0.f ? e : 0.2f * e;
        float p = __expf(e);
        q0 += p;
        a = fmaf(p, bf2f(h[(size_t)s * 64 + t]), a);
    }
    float sum = (q0 + q1) + (q2 + q3);
    float rd = 1.f / (sum + 1e-16f);
    float acc = (a + b) + (c + d);
    float v = elu1(acc * rd + bias[t]);
    float prod = v * Wc[t];
#pragma unroll
    for (int off = 32; off >= 1; off >>= 1) prod += __shfl_down(prod, off);
    if (t == 0) out[n] = 1.f / (1.f + __expf(-(prod + bc[0])));
}

extern "C" void kernel_launch(void* const* d_in, const int* in_sizes, int n_in,
                              void* d_out, int out_size, void* d_ws, size_t ws_size,
                              hipStream_t stream) {
    const float* x   = (const float*)d_in[0];
    const int*   ei  = (const int*)d_in[1];
    const int* src_row = ei;
    const int* dst_row = ei + N_EDGES;
    const float* W1  = (const float*)d_in[2];
    const float* as1 = (const float*)d_in[3];
    const float* ad1 = (const float*)d_in[4];
    const float* b1  = (const float*)d_in[5];
    const float* W2  = (const float*)d_in[6];
    const float* as2 = (const float*)d_in[7];
    const float* ad2 = (const float*)d_in[8];
    const float* b2  = (const float*)d_in[9];
    const float* W3  = (const float*)d_in[10];
    const float* as3 = (const float*)d_in[11];
    const float* ad3 = (const float*)d_in[12];
    const float* b3  = (const float*)d_in[13];
    const float* Wc  = (const float*)d_in[14];
    const float* bc  = (const float*)d_in[15];

    char* w = (char*)d_ws;
    auto alloc = [&](size_t bytes) -> void* {
        void* ptr = (void*)w;
        w += (bytes + 255) & ~(size_t)255;
        return ptr;
    };
    int*   deg    = (int*)alloc((size_t)N_NODES * 4);
    int*   rowptr = (int*)alloc((size_t)(N_NODES + 1) * 4);
    int*   cursor = (int*)alloc((size_t)N_NODES * 4);
    int*   srcs   = (int*)alloc((size_t)E_TOT * 4);
    int*   psum   = (int*)alloc((size_t)NBLK * 4);
    float* ssrc   = (float*)alloc((size_t)N_NODES * HEADS * 4);
    float* sdst   = (float*)alloc((size_t)N_NODES * HEADS * 4);
    unsigned short* hbf = (unsigned short*)alloc((size_t)N_NODES * HC * 2);  // bf16 h (GEMM out)
    unsigned short* gbf = (unsigned short*)alloc((size_t)N_NODES * HC * 2);  // agg out (bf16)
    unsigned short* w2t = (unsigned short*)alloc((size_t)512 * 512 * 2);
    unsigned short* w3t = (unsigned short*)alloc((size_t)64 * 512 * 2);

    hipMemsetAsync(deg, 0, (size_t)N_NODES * 4, stream);

    const int EB = (E_TOT + 255) / 256;
    hist_kernel<<<EB, 256, 0, stream>>>(dst_row, deg);
    deg_partial_kernel<<<NBLK, 256, 0, stream>>>(deg, psum);
    scan_partial_kernel<<<1, 256, 0, stream>>>(psum);
    rowptr_kernel<<<NBLK, 256, 0, stream>>>(deg, psum, rowptr, cursor);
    scatter_kernel<<<EB, 256, 0, stream>>>(src_row, dst_row, cursor, srcs);

    // weight transpose (bf16, tiny; once per call)
    wtrans_kernel<512><<<(512 * 512 + 255) / 256, 256, 0, stream>>>(W2, w2t);
    wtrans_kernel<64><<<(512 * 64 + 255) / 256, 256, 0, stream>>>(W3, w3t);

    const int NB  = (N_NODES + 255) / 256;
    const int MB128 = (N_NODES + 127) / 128;                 // 391
    const int G2 = ((MB128 + 7) / 8) * 32;                   // 49 groups x (4x * 8y) = 1568
    const int MB64 = (N_NODES + 63) / 64;                    // 782
    const int G3 = ((MB64 + 7) / 8) * 8;                     // 784

    // ---- layer 1: fused x@W1 + score -> hbf, ssrc/sdst -> fused softmax+agg -> gbf ----
    gemm5score_kernel<<<N_NODES / 4, 256, 0, stream>>>(x, W1, as1, ad1, hbf, ssrc, sdst);
    agg8sf_kernel<<<N_NODES, 256, 0, stream>>>(hbf, ssrc, sdst, rowptr, srcs, b1, gbf);

    // ---- layer 2: gbf @ W2 (bf16 MFMA + fused score) -> fused softmax+agg -> gbf ----
    gemm_mfma<128, 128, 2, 2, 4, 8, true><<<G2, 256, 0, stream>>>(
        gbf, w2t, hbf, as2, ad2, ssrc, sdst, N_NODES, 512, 511);
    agg8sf_kernel<<<N_NODES, 256, 0, stream>>>(hbf, ssrc, sdst, rowptr, srcs, b2, gbf);

    // ---- layer 3: gbf @ W3 (BM=64, fused score, 1 head) -> fused softmax+agg+cls -> d_out ----
    gemm_mfma<64, 64, 2, 1, 1, 1, true><<<G3, 128, 0, stream>>>(
        gbf, w3t, hbf, as3, ad3, ssrc, sdst, N_NODES, 64, 63);
    agg1cls_kernel<<<N_NODES, 64, 0, stream>>>(hbf, ssrc, sdst, rowptr, srcs, b3, Wc, bc,
                                               (float*)d_out);
}